// Round 11
// baseline (254.765 us; speedup 1.0000x reference)
//
#include <hip/hip_runtime.h>
#include <math.h>

// B=4, H=W=64, C=256, DG=8, K=3, cpg=32; coarse: [4,32,32,256]

typedef __attribute__((ext_vector_type(8))) short bf16x8;
typedef __attribute__((ext_vector_type(4))) short bf16x4;
typedef __attribute__((ext_vector_type(4))) float f32x4;
#define MFMA16(a,b,c) __builtin_amdgcn_mfma_f32_16x16x32_bf16(a,b,c,0,0,0)

__device__ inline short f2b(float x){
  union { float f; unsigned u; } v; v.f = x;
  unsigned r = v.u + 0x7FFFu + ((v.u >> 16) & 1u);
  return (short)(r >> 16);
}
__device__ inline float b2f(short s){
  union { unsigned u; float f; } v;
  v.u = ((unsigned)(unsigned short)s) << 16;
  return v.f;
}

// workspace layout (float offsets)
#define OFS_GATE  1024u
#define OFS_PART  2048u        // f32 [256][256] gap partials
#define OFS_CUPB  264192u      // bf16 [4][64][64][256]
#define OFS_FCAL  4458496u     // f32  [16384][256]
#define OFS_ALGB  8652800u     // bf16 [16384][512]
#define OFS_OM    12847104u    // f32  [16384][216]
#define OFS_DWB   16386048u    // bf16 frag [72][16][64][8]
#define OFS_OMWB  16680960u    // bf16 frag [144][16][64][8]
#define OFS_SWB   17270784u    // bf16 frag [8][16][64][8]
#define OFS_OWB   17401856u    // bf16 frag [16][32][64][8]

// GAP partials: 256 blocks (b*64+chunk), float4 loads, LDS reduce, no atomics
__global__ __launch_bounds__(256) void k_gap(const float* __restrict__ fine,
                                             float* __restrict__ part){
  __shared__ float red[4*256];
  int b = blockIdx.x >> 6, chunk = blockIdx.x & 63;
  int c4 = threadIdx.x & 63, rl = threadIdx.x >> 6;
  const float4* F4 = (const float4*)fine;
  float4 s = {0.f,0.f,0.f,0.f};
  for (int it = 0; it < 16; ++it){
    int row = chunk*64 + it*4 + rl;
    float4 v = F4[((size_t)(b*4096 + row))*64 + c4];
    s.x += v.x; s.y += v.y; s.z += v.z; s.w += v.w;
  }
  *(float4*)&red[rl*256 + c4*4] = s;
  __syncthreads();
  int c = threadIdx.x;
  part[(size_t)blockIdx.x*256 + c] = red[c] + red[256+c] + red[512+c] + red[768+c];
}

// fused: attn (blocks 0-3) + weight frag cvt (dwb/omwb/owb/swb) + upsample->bf16
__global__ __launch_bounds__(256) void k_misc(const float* __restrict__ part,
                                              const float* __restrict__ aw,
                                              float* __restrict__ gate,
                                              const float* __restrict__ dw,
                                              const float* __restrict__ omw,
                                              const float* __restrict__ ow,
                                              const float* __restrict__ sw,
                                              short* __restrict__ dwb,
                                              short* __restrict__ omwb,
                                              short* __restrict__ owb,
                                              short* __restrict__ swb,
                                              const float* __restrict__ coarse,
                                              short* __restrict__ cupb){
  int blk = blockIdx.x;
  if (blk < 4){
    __shared__ float m[256];
    int b = blk, f = threadIdx.x;
    float sm = 0.f;
    for (int ch = 0; ch < 64; ++ch) sm += part[(size_t)(b*64 + ch)*256 + f];
    m[f] = sm * (1.f/4096.f);
    __syncthreads();
    float s = 0.f;
    for (int c = 0; c < 256; ++c) s += m[c] * aw[c*256 + f];
    gate[b*256 + f] = 1.f + 1.f/(1.f + expf(-s));
  } else if (blk < 292){
    int t = (blk - 4)*256 + threadIdx.x;         // 73728
    int l = t & 63, nt = (t >> 6) & 15, ksg = t >> 10;
    int n = nt*16 + (l & 15);
    int kb = ksg*32 + (l >> 4)*8;
    bf16x8 o;
#pragma unroll
    for (int j = 0; j < 8; ++j) o[j] = f2b(dw[(size_t)(kb + j)*256 + n]);
    ((bf16x8*)dwb)[t] = o;
  } else if (blk < 868){
    int t = (blk - 292)*256 + threadIdx.x;       // 147456
    int l = t & 63, nt = (t >> 6) & 15, ksg = t >> 10;
    int n = nt*16 + (l & 15);
    int kb = ksg*32 + (l >> 4)*8;
    bf16x8 o;
#pragma unroll
    for (int j = 0; j < 8; ++j)
      o[j] = (n < 216) ? f2b(omw[(size_t)(kb + j)*216 + n]) : (short)0;
    ((bf16x8*)omwb)[t] = o;
  } else if (blk < 996){
    int t = (blk - 868)*256 + threadIdx.x;       // 32768
    int l = t & 63, nt = (t >> 6) & 31, ksg = t >> 11;
    int n = nt*16 + (l & 15);
    int kb = ksg*32 + (l >> 4)*8;
    float sc = (kb >= 256) ? 2.f : 1.f;
    bf16x8 o;
#pragma unroll
    for (int j = 0; j < 8; ++j) o[j] = f2b(sc * ow[(size_t)(kb + j)*512 + n]);
    ((bf16x8*)owb)[t] = o;
  } else if (blk < 1124){
    int t = (blk - 996)*256 + threadIdx.x;       // 32768
    int l = t & 63, nt = (t >> 6) & 15, ksg = t >> 10;
    int n = nt*16 + (l & 15);
    int kb = ksg*32 + (l >> 4)*8;
    bf16x8 o;
#pragma unroll
    for (int j = 0; j < 8; ++j) o[j] = f2b(sw[(size_t)(kb + j)*256 + n]);
    ((bf16x8*)swb)[t] = o;
  } else {
    int idx = (blk - 1124)*256 + threadIdx.x;    // B*64*64*64 4-ch units
    int c4 = idx & 63, x = (idx >> 6) & 63, y = (idx >> 12) & 63, b = idx >> 18;
    float fy = 0.5f*y - 0.25f, fx = 0.5f*x - 0.25f;
    float yf = floorf(fy), xf = floorf(fx);
    float wy = fy - yf, wx = fx - xf;
    int r0 = max(0, min(31, (int)yf)), r1 = max(0, min(31, (int)yf + 1));
    int c0 = max(0, min(31, (int)xf)), c1 = max(0, min(31, (int)xf + 1));
    const float4* src = (const float4*)coarse;
    float4 v00 = src[((b*32 + r0)*32 + c0)*64 + c4];
    float4 v01 = src[((b*32 + r0)*32 + c1)*64 + c4];
    float4 v10 = src[((b*32 + r1)*32 + c0)*64 + c4];
    float4 v11 = src[((b*32 + r1)*32 + c1)*64 + c4];
    float w00 = (1.f-wy)*(1.f-wx), w01 = (1.f-wy)*wx, w10 = wy*(1.f-wx), w11 = wy*wx;
    bf16x4 o = { f2b(v00.x*w00 + v01.x*w01 + v10.x*w10 + v11.x*w11),
                 f2b(v00.y*w00 + v01.y*w01 + v10.y*w10 + v11.y*w11),
                 f2b(v00.z*w00 + v01.z*w01 + v10.z*w10 + v11.z*w11),
                 f2b(v00.w*w00 + v01.w*w01 + v10.w*w10 + v11.w*w11) };
    ((bf16x4*)cupb)[idx] = o;
  }
}

// fused fcal+align: 512 threads / 8 waves (16 waves/CU) to hide L2 weight
// latency; BM=32 grid 512. GEMM1: wave owns 32 n-cols; GEMM2: 64 n-cols.
// XCD-aware bijective swizzle for cupb K-tail locality.
#define FST 264
__global__ __launch_bounds__(512) void k_fa(const float* __restrict__ fine,
                                            const float* __restrict__ gate,
                                            const short* __restrict__ swb,
                                            const short* __restrict__ owb,
                                            const short* __restrict__ cupb,
                                            float* __restrict__ fcal,
                                            short* __restrict__ algb){
  __shared__ float g4[256];
  __shared__ short ab[32*FST];
  int bid = ((blockIdx.x & 7) << 6) | (blockIdx.x >> 3);  // bijective, 512%8==0
  int m0 = bid*32, b = m0 >> 12;
  int tid = threadIdx.x, lane = tid & 63, wave = tid >> 6;  // 8 waves
  int arow = lane & 15, aquad = lane >> 4;
  if (tid < 256) g4[tid] = gate[b*256 + tid];
  __syncthreads();
  const float4* F4 = (const float4*)(fine + (size_t)m0*256);
  const float4* G4 = (const float4*)g4;
  for (int it = 0; it < 4; ++it){
    int idx = it*512 + tid;               // 2048 = 32 rows x 64 c4
    int row = idx >> 6, c4 = idx & 63;
    float4 v = F4[row*64 + c4];
    float4 gg = G4[c4];
    bf16x4 s4 = { f2b(v.x*gg.x), f2b(v.y*gg.y), f2b(v.z*gg.z), f2b(v.w*gg.w) };
    *(bf16x4*)&ab[row*FST + c4*4] = s4;
  }
  __syncthreads();
  f32x4 acc[2][2];
#pragma unroll
  for (int s = 0; s < 2; ++s)
#pragma unroll
    for (int t = 0; t < 2; ++t) acc[s][t] = (f32x4){0.f,0.f,0.f,0.f};
  const bf16x8* W8 = (const bf16x8*)swb;
  for (int ks = 0; ks < 8; ++ks){
    bf16x8 a0 = *(const bf16x8*)&ab[arow*FST + ks*32 + aquad*8];
    bf16x8 a1 = *(const bf16x8*)&ab[(16 + arow)*FST + ks*32 + aquad*8];
    const bf16x8* wp = W8 + ((size_t)(ks*16 + wave*2))*64 + lane;
#pragma unroll
    for (int t = 0; t < 2; ++t){
      bf16x8 bw = wp[t*64];
      acc[0][t] = MFMA16(a0, bw, acc[0][t]);
      acc[1][t] = MFMA16(a1, bw, acc[1][t]);
    }
  }
  __syncthreads();
#pragma unroll
  for (int t = 0; t < 2; ++t){
    int f = wave*32 + t*16 + arow;
#pragma unroll
    for (int s = 0; s < 2; ++s)
#pragma unroll
      for (int r = 0; r < 4; ++r){
        int mloc = s*16 + aquad*4 + r;
        float v = acc[s][t][r];
        fcal[(size_t)(m0 + mloc)*256 + f] = v;
        ab[mloc*FST + f] = f2b(v);
      }
  }
  __syncthreads();
  f32x4 acc2[2][4];
#pragma unroll
  for (int s = 0; s < 2; ++s)
#pragma unroll
    for (int t = 0; t < 4; ++t) acc2[s][t] = (f32x4){0.f,0.f,0.f,0.f};
  const bf16x8* OW8 = (const bf16x8*)owb;
  for (int ks = 0; ks < 16; ++ks){
    bf16x8 a0, a1;
    if (ks < 8){
      a0 = *(const bf16x8*)&ab[arow*FST + ks*32 + aquad*8];
      a1 = *(const bf16x8*)&ab[(16 + arow)*FST + ks*32 + aquad*8];
    } else {
      int ko = (ks - 8)*32 + aquad*8;
      a0 = *(const bf16x8*)(cupb + (size_t)(m0 + arow)*256 + ko);
      a1 = *(const bf16x8*)(cupb + (size_t)(m0 + 16 + arow)*256 + ko);
    }
    const bf16x8* wp = OW8 + ((size_t)(ks*32 + wave*4))*64 + lane;
#pragma unroll
    for (int t = 0; t < 4; ++t){
      bf16x8 bw = wp[t*64];
      acc2[0][t] = MFMA16(a0, bw, acc2[0][t]);
      acc2[1][t] = MFMA16(a1, bw, acc2[1][t]);
    }
  }
#pragma unroll
  for (int t = 0; t < 4; ++t){
    int n = wave*64 + t*16 + arow;
#pragma unroll
    for (int s = 0; s < 2; ++s)
#pragma unroll
      for (int r = 0; r < 4; ++r){
        int m = m0 + s*16 + aquad*4 + r;
        algb[(size_t)m*512 + n] = f2b(acc2[s][t][r]);
      }
  }
}

// om conv3x3 as MFMA implicit GEMM. v2 (round-5 best config, BANKED: six
// structural variants all landed 57-96us; latency-pinned ~58us, not touched).
// BM=64, BN=256, 1x8 waves, acc[4][2], 264-pad, 6 stage phases, weight
// prefetch. Mask channels pre-sigmoided for k_dcn.
#define XST2 264
__global__ __launch_bounds__(512) void k_om(const short* __restrict__ algb,
                                            const short* __restrict__ omwb,
                                            const float* __restrict__ omb,
                                            float* __restrict__ om){
  __shared__ short xbuf[66*XST2];   // 34848 B
  int blk = ((blockIdx.x & 7) << 5) | (blockIdx.x >> 3);  // bijective, 256%8==0
  int m0 = blk*64;
  int b = m0 >> 12, y = (m0 >> 6) & 63;
  int tid = threadIdx.x;
  int lane = tid & 63, wave = tid >> 6;      // 8 waves
  int arow = lane & 15, aquad = lane >> 4;
  f32x4 acc[4][2];
#pragma unroll
  for (int mi = 0; mi < 4; ++mi)
#pragma unroll
    for (int t = 0; t < 2; ++t) acc[mi][t] = (f32x4){0.f,0.f,0.f,0.f};
  const bf16x8* W8 = (const bf16x8*)omwb;
  for (int ky = 0; ky < 3; ++ky){
    int yy = y + ky - 1;
    if ((unsigned)yy >= 64u) continue;       // block-uniform
    const short* srow = algb + (size_t)((b*64 + yy)*64)*512;
    for (int h = 0; h < 2; ++h){
      __syncthreads();
      for (int it = 0; it < 5; ++it){
        int u = it*512 + tid;                // 2112 = 66 cols x 32 units
        if (u < 2112){
          int xx = u >> 5, cu = u & 31;
          int gx = xx - 1;
          bf16x8 v = (bf16x8){0,0,0,0,0,0,0,0};
          if ((unsigned)gx < 64u)
            v = *(const bf16x8*)(srow + (size_t)gx*512 + h*256 + cu*8);
          *(bf16x8*)&xbuf[xx*XST2 + cu*8] = v;
        }
      }
      __syncthreads();
#pragma unroll
      for (int kx = 0; kx < 3; ++kx){
        // wb: base for (ky,kx,h,s=0); per-s stride = 16*64 bf16x8 = 1024
        const bf16x8* wb = W8 + ((size_t)((ky*48 + kx*16 + h*8)*16 + wave*2))*64 + lane;
        bf16x8 c0 = wb[0], c1 = wb[64];
        for (int s = 0; s < 8; ++s){
          bf16x8 a[4];
#pragma unroll
          for (int mi = 0; mi < 4; ++mi)
            a[mi] = *(const bf16x8*)&xbuf[(mi*16 + arow + kx)*XST2 + s*32 + aquad*8];
          bf16x8 n0, n1;
          if (s < 7){ n0 = wb[(s+1)*1024]; n1 = wb[(s+1)*1024 + 64]; }
#pragma unroll
          for (int mi = 0; mi < 4; ++mi) acc[mi][0] = MFMA16(a[mi], c0, acc[mi][0]);
#pragma unroll
          for (int mi = 0; mi < 4; ++mi) acc[mi][1] = MFMA16(a[mi], c1, acc[mi][1]);
          if (s < 7){ c0 = n0; c1 = n1; }
        }
      }
    }
  }
#pragma unroll
  for (int t = 0; t < 2; ++t){
    int f = wave*32 + t*16 + arow;
    if (f < 216){
      float bias = omb[f];
      bool is_mask = (f >= 144);
#pragma unroll
      for (int mi = 0; mi < 4; ++mi)
#pragma unroll
        for (int r = 0; r < 4; ++r){
          int m = m0 + mi*16 + aquad*4 + r;
          float v = acc[mi][t][r] + bias;
          if (is_mask) v = 1.f/(1.f + expf(-v));
          om[(size_t)m*216 + f] = v;
        }
    }
  }
}

// DCNv2: M-tile 32, 512-thread blocks (2 blocks/CU). Gather phase v3:
// phase-wide PARAM BATCH -- all 6 iterations' om loads (12 vmem) issued
// together at phase start (one latency instead of 6 partially-hidden ones;
// om rows may be cross-XCD -> L3-latency), params held in fully-unrolled
// register arrays (~54 VGPR, static indexing); then the proven 2-deep gather
// pipeline runs off registers. launch_bounds(512,4) caps VGPR at 128 to
// guarantee 2 blocks/CU. Weight prefetch kept in ks-loop.
#define VST 776
__global__ __launch_bounds__(512, 4) void k_dcn(const short* __restrict__ cupb,
                                                const float* __restrict__ om,
                                                const short* __restrict__ dwb,
                                                const float* __restrict__ db,
                                                const float* __restrict__ fcal,
                                                float* __restrict__ out){
  __shared__ short valb[32*VST];   // 49664 B
  int bid = ((blockIdx.x & 7) << 6) | (blockIdx.x >> 3);  // XCD swizzle, bijective
  int m0 = bid*32;
  int b = m0 >> 12, y = (m0 & 4095) >> 6, x0 = m0 & 63;
  int tid = threadIdx.x;
  int lane = tid & 63, wave = tid >> 6;    // 8 waves
  int unit = tid >> 2, lane4 = tid & 3;    // 128 units x 4 lanes
  int arow = lane & 15, aquad = lane >> 4;
  f32x4 acc[2][2];
#pragma unroll
  for (int s = 0; s < 2; ++s)
#pragma unroll
    for (int t = 0; t < 2; ++t) acc[s][t] = (f32x4){0.f,0.f,0.f,0.f};
  const short* cpb = cupb + (size_t)b*4096*256;
  const bf16x8* W8 = (const bf16x8*)dwb;

  for (int ph = 0; ph < 3; ++ph){
    __syncthreads();
    // ---- param batch: all 6 iterations' om loads in flight together ----
    float pwA[6], pwB[6], pwC[6], pwD[6], pmv[6];
    int piy[6], pix[6], pcf[6], pdst[6];
#pragma unroll
    for (int it = 0; it < 6; ++it){
      int u = it*128 + unit;
      int i = u / 24; int r = u - i*24; int g = r / 3; int kk = r - g*3;
      const float* omp = om + (size_t)(m0 + i)*216;
      int k = ph*3 + kk;
      float dy = omp[(g*9 + k)*2 + 0];
      float dx = omp[(g*9 + k)*2 + 1];
      pmv[it] = omp[144 + g*9 + k];          // pre-sigmoided in k_om
      float yp = (float)(y + ph - 1) + dy;
      float xp = (float)(x0 + i + kk - 1) + dx;
      float yf = floorf(yp), xf = floorf(xp);
      float wy = yp - yf, wx = xp - xf;
      int iy = (int)yf, ix = (int)xf;
      float wA = (1.f-wy)*(1.f-wx), wB = (1.f-wy)*wx;
      float wC = wy*(1.f-wx), wD = wy*wx;
      bool y0ok = (unsigned)iy < 64u, y1ok = (unsigned)(iy+1) < 64u;
      bool x0ok = (unsigned)ix < 64u, x1ok = (unsigned)(ix+1) < 64u;
      if (!(y0ok && x0ok)) wA = 0.f;
      if (!(y0ok && x1ok)) wB = 0.f;
      if (!(y1ok && x0ok)) wC = 0.f;
      if (!(y1ok && x1ok)) wD = 0.f;
      pwA[it] = wA; pwB[it] = wB; pwC[it] = wC; pwD[it] = wD;
      piy[it] = iy; pix[it] = ix;
      pcf[it] = g*32 + lane4*8;
      pdst[it] = i*VST + kk*256 + g*32 + lane4*8;
    }
    // ---- 2-deep gather pipeline off registers ----
    bf16x8 L0[2], L1[2], L2[2], L3[2];
#define DCN_GISS(S, IT)                                                       \
    {                                                                         \
      int y0c = min(max(piy[IT], 0), 63), y1c = min(max(piy[IT] + 1, 0), 63); \
      int x0c = min(max(pix[IT], 0), 63), x1c = min(max(pix[IT] + 1, 0), 63); \
      int cofs = pcf[IT];                                                     \
      L0[S] = *(const bf16x8*)(cpb + (size_t)(y0c*64 + x0c)*256 + cofs);      \
      L1[S] = *(const bf16x8*)(cpb + (size_t)(y0c*64 + x1c)*256 + cofs);      \
      L2[S] = *(const bf16x8*)(cpb + (size_t)(y1c*64 + x0c)*256 + cofs);      \
      L3[S] = *(const bf16x8*)(cpb + (size_t)(y1c*64 + x1c)*256 + cofs);      \
    }
    DCN_GISS(0, 0)
#pragma unroll
    for (int it = 0; it < 6; ++it){
      int c = it & 1;
      if (it < 5){ DCN_GISS(c ^ 1, it + 1) }
      bf16x8 o;
#pragma unroll
      for (int j = 0; j < 8; ++j){
        float v = pwA[it]*b2f(L0[c][j]) + pwB[it]*b2f(L1[c][j])
                + pwC[it]*b2f(L2[c][j]) + pwD[it]*b2f(L3[c][j]);
        o[j] = f2b(v * pmv[it]);
      }
      *(bf16x8*)&valb[pdst[it]] = o;
    }
#undef DCN_GISS
    __syncthreads();
    // ks-loop with weight prefetch: per-ks stride = 16*64 bf16x8 = 1024
    const bf16x8* wb = W8 + ((size_t)((ph*24)*16 + wave*2))*64 + lane;
    bf16x8 c0 = wb[0], c1 = wb[64];
    for (int ks = 0; ks < 24; ++ks){
      bf16x8 a0 = *(const bf16x8*)&valb[arow*VST + ks*32 + aquad*8];
      bf16x8 a1 = *(const bf16x8*)&valb[(16 + arow)*VST + ks*32 + aquad*8];
      bf16x8 n0, n1;
      if (ks < 23){ n0 = wb[(ks+1)*1024]; n1 = wb[(ks+1)*1024 + 64]; }
      acc[0][0] = MFMA16(a0, c0, acc[0][0]);
      acc[1][0] = MFMA16(a1, c0, acc[1][0]);
      acc[0][1] = MFMA16(a0, c1, acc[0][1]);
      acc[1][1] = MFMA16(a1, c1, acc[1][1]);
      if (ks < 23){ c0 = n0; c1 = n1; }
    }
  }
#pragma unroll
  for (int t = 0; t < 2; ++t){
    int f = wave*32 + t*16 + (lane & 15);
    float bias = db[f];
#pragma unroll
    for (int s = 0; s < 2; ++s)
#pragma unroll
      for (int r = 0; r < 4; ++r){
        int m = m0 + s*16 + aquad*4 + r;
        out[(size_t)m*256 + f] = fmaxf(acc[s][t][r] + bias, 0.f) + fcal[(size_t)m*256 + f];
      }
  }
}

extern "C" void kernel_launch(void* const* d_in, const int* in_sizes, int n_in,
                              void* d_out, int out_size, void* d_ws, size_t ws_size,
                              hipStream_t stream){
  const float* fine     = (const float*)d_in[0];
  const float* coarse   = (const float*)d_in[1];
  const float* attend_w = (const float*)d_in[2];
  const float* select_w = (const float*)d_in[3];
  const float* offset_w = (const float*)d_in[4];
  const float* om_w     = (const float*)d_in[5];
  const float* om_b     = (const float*)d_in[6];
  const float* dcn_w    = (const float*)d_in[7];
  const float* dcn_b    = (const float*)d_in[8];
  float* out = (float*)d_out;
  float* ws  = (float*)d_ws;

  float* gate = ws + OFS_GATE;
  float* part = ws + OFS_PART;
  short* cupb = (short*)(ws + OFS_CUPB);
  float* fcal = ws + OFS_FCAL;
  short* algb = (short*)(ws + OFS_ALGB);
  float* om   = ws + OFS_OM;
  short* dwb  = (short*)(ws + OFS_DWB);
  short* omwb = (short*)(ws + OFS_OMWB);
  short* swb  = (short*)(ws + OFS_SWB);
  short* owb  = (short*)(ws + OFS_OWB);

  hipLaunchKernelGGL(k_gap,  dim3(256),  dim3(256), 0, stream, fine, part);
  hipLaunchKernelGGL(k_misc, dim3(5220), dim3(256), 0, stream, part, attend_w, gate,
                     dcn_w, om_w, offset_w, select_w, dwb, omwb, owb, swb, coarse, cupb);
  hipLaunchKernelGGL(k_fa,   dim3(512),  dim3(512), 0, stream, fine, gate, swb, owb,
                     cupb, fcal, algb);
  hipLaunchKernelGGL(k_om,   dim3(256),  dim3(512), 0, stream, algb, omwb, om_b, om);
  hipLaunchKernelGGL(k_dcn,  dim3(512),  dim3(512), 0, stream, cupb, om, dwb, dcn_b, fcal, out);
  (void)in_sizes; (void)n_in; (void)out_size; (void)ws_size;
}

// Round 12
// 232.478 us; speedup vs baseline: 1.0959x; 1.0959x over previous
//
#include <hip/hip_runtime.h>
#include <math.h>

// B=4, H=W=64, C=256, DG=8, K=3, cpg=32; coarse: [4,32,32,256]

typedef __attribute__((ext_vector_type(8))) short bf16x8;
typedef __attribute__((ext_vector_type(4))) short bf16x4;
typedef __attribute__((ext_vector_type(4))) float f32x4;
#define MFMA16(a,b,c) __builtin_amdgcn_mfma_f32_16x16x32_bf16(a,b,c,0,0,0)

__device__ inline short f2b(float x){
  union { float f; unsigned u; } v; v.f = x;
  unsigned r = v.u + 0x7FFFu + ((v.u >> 16) & 1u);
  return (short)(r >> 16);
}
__device__ inline float b2f(short s){
  union { unsigned u; float f; } v;
  v.u = ((unsigned)(unsigned short)s) << 16;
  return v.f;
}

// workspace layout (float offsets)
#define OFS_GATE  1024u
#define OFS_PART  2048u        // f32 [256][256] gap partials
#define OFS_CUPB  264192u      // bf16 [4][64][64][256]
#define OFS_FCAL  4458496u     // f32  [16384][256]
#define OFS_ALGB  8652800u     // bf16 [16384][512]
#define OFS_OM    12847104u    // f32  [16384][216]
#define OFS_DWB   16386048u    // bf16 frag [72][16][64][8]
#define OFS_OMWB  16680960u    // bf16 frag [144][16][64][8]
#define OFS_SWB   17270784u    // bf16 frag [8][16][64][8]
#define OFS_OWB   17401856u    // bf16 frag [16][32][64][8]

// GAP partials: 256 blocks (b*64+chunk), float4 loads, LDS reduce, no atomics
__global__ __launch_bounds__(256) void k_gap(const float* __restrict__ fine,
                                             float* __restrict__ part){
  __shared__ float red[4*256];
  int b = blockIdx.x >> 6, chunk = blockIdx.x & 63;
  int c4 = threadIdx.x & 63, rl = threadIdx.x >> 6;
  const float4* F4 = (const float4*)fine;
  float4 s = {0.f,0.f,0.f,0.f};
  for (int it = 0; it < 16; ++it){
    int row = chunk*64 + it*4 + rl;
    float4 v = F4[((size_t)(b*4096 + row))*64 + c4];
    s.x += v.x; s.y += v.y; s.z += v.z; s.w += v.w;
  }
  *(float4*)&red[rl*256 + c4*4] = s;
  __syncthreads();
  int c = threadIdx.x;
  part[(size_t)blockIdx.x*256 + c] = red[c] + red[256+c] + red[512+c] + red[768+c];
}

// fused: attn (blocks 0-3) + weight frag cvt (dwb/omwb/owb/swb) + upsample->bf16
__global__ __launch_bounds__(256) void k_misc(const float* __restrict__ part,
                                              const float* __restrict__ aw,
                                              float* __restrict__ gate,
                                              const float* __restrict__ dw,
                                              const float* __restrict__ omw,
                                              const float* __restrict__ ow,
                                              const float* __restrict__ sw,
                                              short* __restrict__ dwb,
                                              short* __restrict__ omwb,
                                              short* __restrict__ owb,
                                              short* __restrict__ swb,
                                              const float* __restrict__ coarse,
                                              short* __restrict__ cupb){
  int blk = blockIdx.x;
  if (blk < 4){
    __shared__ float m[256];
    int b = blk, f = threadIdx.x;
    float sm = 0.f;
    for (int ch = 0; ch < 64; ++ch) sm += part[(size_t)(b*64 + ch)*256 + f];
    m[f] = sm * (1.f/4096.f);
    __syncthreads();
    float s = 0.f;
    for (int c = 0; c < 256; ++c) s += m[c] * aw[c*256 + f];
    gate[b*256 + f] = 1.f + 1.f/(1.f + expf(-s));
  } else if (blk < 292){
    int t = (blk - 4)*256 + threadIdx.x;         // 73728
    int l = t & 63, nt = (t >> 6) & 15, ksg = t >> 10;
    int n = nt*16 + (l & 15);
    int kb = ksg*32 + (l >> 4)*8;
    bf16x8 o;
#pragma unroll
    for (int j = 0; j < 8; ++j) o[j] = f2b(dw[(size_t)(kb + j)*256 + n]);
    ((bf16x8*)dwb)[t] = o;
  } else if (blk < 868){
    int t = (blk - 292)*256 + threadIdx.x;       // 147456
    int l = t & 63, nt = (t >> 6) & 15, ksg = t >> 10;
    int n = nt*16 + (l & 15);
    int kb = ksg*32 + (l >> 4)*8;
    bf16x8 o;
#pragma unroll
    for (int j = 0; j < 8; ++j)
      o[j] = (n < 216) ? f2b(omw[(size_t)(kb + j)*216 + n]) : (short)0;
    ((bf16x8*)omwb)[t] = o;
  } else if (blk < 996){
    int t = (blk - 868)*256 + threadIdx.x;       // 32768
    int l = t & 63, nt = (t >> 6) & 31, ksg = t >> 11;
    int n = nt*16 + (l & 15);
    int kb = ksg*32 + (l >> 4)*8;
    float sc = (kb >= 256) ? 2.f : 1.f;
    bf16x8 o;
#pragma unroll
    for (int j = 0; j < 8; ++j) o[j] = f2b(sc * ow[(size_t)(kb + j)*512 + n]);
    ((bf16x8*)owb)[t] = o;
  } else if (blk < 1124){
    int t = (blk - 996)*256 + threadIdx.x;       // 32768
    int l = t & 63, nt = (t >> 6) & 15, ksg = t >> 10;
    int n = nt*16 + (l & 15);
    int kb = ksg*32 + (l >> 4)*8;
    bf16x8 o;
#pragma unroll
    for (int j = 0; j < 8; ++j) o[j] = f2b(sw[(size_t)(kb + j)*256 + n]);
    ((bf16x8*)swb)[t] = o;
  } else {
    int idx = (blk - 1124)*256 + threadIdx.x;    // B*64*64*64 4-ch units
    int c4 = idx & 63, x = (idx >> 6) & 63, y = (idx >> 12) & 63, b = idx >> 18;
    float fy = 0.5f*y - 0.25f, fx = 0.5f*x - 0.25f;
    float yf = floorf(fy), xf = floorf(fx);
    float wy = fy - yf, wx = fx - xf;
    int r0 = max(0, min(31, (int)yf)), r1 = max(0, min(31, (int)yf + 1));
    int c0 = max(0, min(31, (int)xf)), c1 = max(0, min(31, (int)xf + 1));
    const float4* src = (const float4*)coarse;
    float4 v00 = src[((b*32 + r0)*32 + c0)*64 + c4];
    float4 v01 = src[((b*32 + r0)*32 + c1)*64 + c4];
    float4 v10 = src[((b*32 + r1)*32 + c0)*64 + c4];
    float4 v11 = src[((b*32 + r1)*32 + c1)*64 + c4];
    float w00 = (1.f-wy)*(1.f-wx), w01 = (1.f-wy)*wx, w10 = wy*(1.f-wx), w11 = wy*wx;
    bf16x4 o = { f2b(v00.x*w00 + v01.x*w01 + v10.x*w10 + v11.x*w11),
                 f2b(v00.y*w00 + v01.y*w01 + v10.y*w10 + v11.y*w11),
                 f2b(v00.z*w00 + v01.z*w01 + v10.z*w10 + v11.z*w11),
                 f2b(v00.w*w00 + v01.w*w01 + v10.w*w10 + v11.w*w11) };
    ((bf16x4*)cupb)[idx] = o;
  }
}

// fused fcal+align: 512 threads / 8 waves (16 waves/CU) to hide L2 weight
// latency; BM=32 grid 512. GEMM1: wave owns 32 n-cols; GEMM2: 64 n-cols.
// XCD-aware bijective swizzle for cupb K-tail locality.
#define FST 264
__global__ __launch_bounds__(512) void k_fa(const float* __restrict__ fine,
                                            const float* __restrict__ gate,
                                            const short* __restrict__ swb,
                                            const short* __restrict__ owb,
                                            const short* __restrict__ cupb,
                                            float* __restrict__ fcal,
                                            short* __restrict__ algb){
  __shared__ float g4[256];
  __shared__ short ab[32*FST];
  int bid = ((blockIdx.x & 7) << 6) | (blockIdx.x >> 3);  // bijective, 512%8==0
  int m0 = bid*32, b = m0 >> 12;
  int tid = threadIdx.x, lane = tid & 63, wave = tid >> 6;  // 8 waves
  int arow = lane & 15, aquad = lane >> 4;
  if (tid < 256) g4[tid] = gate[b*256 + tid];
  __syncthreads();
  const float4* F4 = (const float4*)(fine + (size_t)m0*256);
  const float4* G4 = (const float4*)g4;
  for (int it = 0; it < 4; ++it){
    int idx = it*512 + tid;               // 2048 = 32 rows x 64 c4
    int row = idx >> 6, c4 = idx & 63;
    float4 v = F4[row*64 + c4];
    float4 gg = G4[c4];
    bf16x4 s4 = { f2b(v.x*gg.x), f2b(v.y*gg.y), f2b(v.z*gg.z), f2b(v.w*gg.w) };
    *(bf16x4*)&ab[row*FST + c4*4] = s4;
  }
  __syncthreads();
  f32x4 acc[2][2];
#pragma unroll
  for (int s = 0; s < 2; ++s)
#pragma unroll
    for (int t = 0; t < 2; ++t) acc[s][t] = (f32x4){0.f,0.f,0.f,0.f};
  const bf16x8* W8 = (const bf16x8*)swb;
  for (int ks = 0; ks < 8; ++ks){
    bf16x8 a0 = *(const bf16x8*)&ab[arow*FST + ks*32 + aquad*8];
    bf16x8 a1 = *(const bf16x8*)&ab[(16 + arow)*FST + ks*32 + aquad*8];
    const bf16x8* wp = W8 + ((size_t)(ks*16 + wave*2))*64 + lane;
#pragma unroll
    for (int t = 0; t < 2; ++t){
      bf16x8 bw = wp[t*64];
      acc[0][t] = MFMA16(a0, bw, acc[0][t]);
      acc[1][t] = MFMA16(a1, bw, acc[1][t]);
    }
  }
  __syncthreads();
#pragma unroll
  for (int t = 0; t < 2; ++t){
    int f = wave*32 + t*16 + arow;
#pragma unroll
    for (int s = 0; s < 2; ++s)
#pragma unroll
      for (int r = 0; r < 4; ++r){
        int mloc = s*16 + aquad*4 + r;
        float v = acc[s][t][r];
        fcal[(size_t)(m0 + mloc)*256 + f] = v;
        ab[mloc*FST + f] = f2b(v);
      }
  }
  __syncthreads();
  f32x4 acc2[2][4];
#pragma unroll
  for (int s = 0; s < 2; ++s)
#pragma unroll
    for (int t = 0; t < 4; ++t) acc2[s][t] = (f32x4){0.f,0.f,0.f,0.f};
  const bf16x8* OW8 = (const bf16x8*)owb;
  for (int ks = 0; ks < 16; ++ks){
    bf16x8 a0, a1;
    if (ks < 8){
      a0 = *(const bf16x8*)&ab[arow*FST + ks*32 + aquad*8];
      a1 = *(const bf16x8*)&ab[(16 + arow)*FST + ks*32 + aquad*8];
    } else {
      int ko = (ks - 8)*32 + aquad*8;
      a0 = *(const bf16x8*)(cupb + (size_t)(m0 + arow)*256 + ko);
      a1 = *(const bf16x8*)(cupb + (size_t)(m0 + 16 + arow)*256 + ko);
    }
    const bf16x8* wp = OW8 + ((size_t)(ks*32 + wave*4))*64 + lane;
#pragma unroll
    for (int t = 0; t < 4; ++t){
      bf16x8 bw = wp[t*64];
      acc2[0][t] = MFMA16(a0, bw, acc2[0][t]);
      acc2[1][t] = MFMA16(a1, bw, acc2[1][t]);
    }
  }
#pragma unroll
  for (int t = 0; t < 4; ++t){
    int n = wave*64 + t*16 + arow;
#pragma unroll
    for (int s = 0; s < 2; ++s)
#pragma unroll
      for (int r = 0; r < 4; ++r){
        int m = m0 + s*16 + aquad*4 + r;
        algb[(size_t)m*512 + n] = f2b(acc2[s][t][r]);
      }
  }
}

// om conv3x3 as MFMA implicit GEMM. v2 (round-5 best config, BANKED: six
// structural variants all landed 57-96us; latency-pinned ~58us, not touched).
// BM=64, BN=256, 1x8 waves, acc[4][2], 264-pad, 6 stage phases, weight
// prefetch. Mask channels pre-sigmoided for k_dcn.
#define XST2 264
__global__ __launch_bounds__(512) void k_om(const short* __restrict__ algb,
                                            const short* __restrict__ omwb,
                                            const float* __restrict__ omb,
                                            float* __restrict__ om){
  __shared__ short xbuf[66*XST2];   // 34848 B
  int blk = ((blockIdx.x & 7) << 5) | (blockIdx.x >> 3);  // bijective, 256%8==0
  int m0 = blk*64;
  int b = m0 >> 12, y = (m0 >> 6) & 63;
  int tid = threadIdx.x;
  int lane = tid & 63, wave = tid >> 6;      // 8 waves
  int arow = lane & 15, aquad = lane >> 4;
  f32x4 acc[4][2];
#pragma unroll
  for (int mi = 0; mi < 4; ++mi)
#pragma unroll
    for (int t = 0; t < 2; ++t) acc[mi][t] = (f32x4){0.f,0.f,0.f,0.f};
  const bf16x8* W8 = (const bf16x8*)omwb;
  for (int ky = 0; ky < 3; ++ky){
    int yy = y + ky - 1;
    if ((unsigned)yy >= 64u) continue;       // block-uniform
    const short* srow = algb + (size_t)((b*64 + yy)*64)*512;
    for (int h = 0; h < 2; ++h){
      __syncthreads();
      for (int it = 0; it < 5; ++it){
        int u = it*512 + tid;                // 2112 = 66 cols x 32 units
        if (u < 2112){
          int xx = u >> 5, cu = u & 31;
          int gx = xx - 1;
          bf16x8 v = (bf16x8){0,0,0,0,0,0,0,0};
          if ((unsigned)gx < 64u)
            v = *(const bf16x8*)(srow + (size_t)gx*512 + h*256 + cu*8);
          *(bf16x8*)&xbuf[xx*XST2 + cu*8] = v;
        }
      }
      __syncthreads();
#pragma unroll
      for (int kx = 0; kx < 3; ++kx){
        // wb: base for (ky,kx,h,s=0); per-s stride = 16*64 bf16x8 = 1024
        const bf16x8* wb = W8 + ((size_t)((ky*48 + kx*16 + h*8)*16 + wave*2))*64 + lane;
        bf16x8 c0 = wb[0], c1 = wb[64];
        for (int s = 0; s < 8; ++s){
          bf16x8 a[4];
#pragma unroll
          for (int mi = 0; mi < 4; ++mi)
            a[mi] = *(const bf16x8*)&xbuf[(mi*16 + arow + kx)*XST2 + s*32 + aquad*8];
          bf16x8 n0, n1;
          if (s < 7){ n0 = wb[(s+1)*1024]; n1 = wb[(s+1)*1024 + 64]; }
#pragma unroll
          for (int mi = 0; mi < 4; ++mi) acc[mi][0] = MFMA16(a[mi], c0, acc[mi][0]);
#pragma unroll
          for (int mi = 0; mi < 4; ++mi) acc[mi][1] = MFMA16(a[mi], c1, acc[mi][1]);
          if (s < 7){ c0 = n0; c1 = n1; }
        }
      }
    }
  }
#pragma unroll
  for (int t = 0; t < 2; ++t){
    int f = wave*32 + t*16 + arow;
    if (f < 216){
      float bias = omb[f];
      bool is_mask = (f >= 144);
#pragma unroll
      for (int mi = 0; mi < 4; ++mi)
#pragma unroll
        for (int r = 0; r < 4; ++r){
          int m = m0 + mi*16 + aquad*4 + r;
          float v = acc[mi][t][r] + bias;
          if (is_mask) v = 1.f/(1.f + expf(-v));
          om[(size_t)m*216 + f] = v;
        }
    }
  }
}

// DCNv2: M-tile 32, 512-thread blocks (2 blocks/CU). Gather phase: r10's
// proven DCN_STAGE pipeline (all slot state inside ONE unrolled loop --
// SROA-safe; r11's cross-loop param arrays spilled to scratch, WRITE_SIZE
// 16k->42k) extended from depth-2 to depth-3: two iterations' loads in
// flight cover the ~450cy om->addr->gather chain instead of one. Slot
// index it%3 is compile-time under full unroll. launch_bounds(512,4).
#define VST 776
__global__ __launch_bounds__(512, 4) void k_dcn(const short* __restrict__ cupb,
                                                const float* __restrict__ om,
                                                const short* __restrict__ dwb,
                                                const float* __restrict__ db,
                                                const float* __restrict__ fcal,
                                                float* __restrict__ out){
  __shared__ short valb[32*VST];   // 49664 B
  int bid = ((blockIdx.x & 7) << 6) | (blockIdx.x >> 3);  // XCD swizzle, bijective
  int m0 = bid*32;
  int b = m0 >> 12, y = (m0 & 4095) >> 6, x0 = m0 & 63;
  int tid = threadIdx.x;
  int lane = tid & 63, wave = tid >> 6;    // 8 waves
  int unit = tid >> 2, lane4 = tid & 3;    // 128 units x 4 lanes
  int arow = lane & 15, aquad = lane >> 4;
  f32x4 acc[2][2];
#pragma unroll
  for (int s = 0; s < 2; ++s)
#pragma unroll
    for (int t = 0; t < 2; ++t) acc[s][t] = (f32x4){0.f,0.f,0.f,0.f};
  const short* cpb = cupb + (size_t)b*4096*256;
  const bf16x8* W8 = (const bf16x8*)dwb;

  for (int ph = 0; ph < 3; ++ph){
    __syncthreads();
    // 768 samples (32 rows x 8 g x 3 taps); 128 units, 6 iters, 8 ch/lane.
    // 3-deep pipeline: PARAM+GATHER(it+1, it+2) in flight before BLEND(it).
    bf16x8 L0[3], L1[3], L2[3], L3[3];
    float pwA[3], pwB[3], pwC[3], pwD[3], pmv[3];
    int pdst[3];
#define DCN_STAGE(S, IT)                                                     \
    {                                                                        \
      int u = (IT)*128 + unit;                                               \
      int i = u / 24; int r = u - i*24; int g = r / 3; int kk = r - g*3;     \
      const float* omp = om + (size_t)(m0 + i)*216;                          \
      int k = ph*3 + kk;                                                     \
      float dy = omp[(g*9 + k)*2 + 0];                                       \
      float dx = omp[(g*9 + k)*2 + 1];                                       \
      float mv = omp[144 + g*9 + k];                                         \
      float yp = (float)(y + ph - 1) + dy;                                   \
      float xp = (float)(x0 + i + kk - 1) + dx;                              \
      float yf = floorf(yp), xf = floorf(xp);                                \
      float wy = yp - yf, wx = xp - xf;                                      \
      int iy = (int)yf, ix = (int)xf;                                        \
      float wA = (1.f-wy)*(1.f-wx), wB = (1.f-wy)*wx;                        \
      float wC = wy*(1.f-wx), wD = wy*wx;                                    \
      bool y0ok = (unsigned)iy < 64u, y1ok = (unsigned)(iy+1) < 64u;         \
      bool x0ok = (unsigned)ix < 64u, x1ok = (unsigned)(ix+1) < 64u;         \
      if (!(y0ok && x0ok)) wA = 0.f;                                         \
      if (!(y0ok && x1ok)) wB = 0.f;                                         \
      if (!(y1ok && x0ok)) wC = 0.f;                                         \
      if (!(y1ok && x1ok)) wD = 0.f;                                         \
      int y0c = min(max(iy, 0), 63), y1c = min(max(iy + 1, 0), 63);          \
      int x0c = min(max(ix, 0), 63), x1c = min(max(ix + 1, 0), 63);          \
      int cofs = g*32 + lane4*8;                                             \
      L0[S] = *(const bf16x8*)(cpb + (size_t)(y0c*64 + x0c)*256 + cofs);     \
      L1[S] = *(const bf16x8*)(cpb + (size_t)(y0c*64 + x1c)*256 + cofs);     \
      L2[S] = *(const bf16x8*)(cpb + (size_t)(y1c*64 + x0c)*256 + cofs);     \
      L3[S] = *(const bf16x8*)(cpb + (size_t)(y1c*64 + x1c)*256 + cofs);     \
      pwA[S] = wA; pwB[S] = wB; pwC[S] = wC; pwD[S] = wD; pmv[S] = mv;       \
      pdst[S] = i*VST + kk*256 + g*32 + lane4*8;                             \
    }
    DCN_STAGE(0, 0)
    DCN_STAGE(1, 1)
#pragma unroll
    for (int it = 0; it < 6; ++it){
      int c = it % 3;
      if (it < 4){ int nx = (it + 2) % 3; DCN_STAGE(nx, it + 2) }
      bf16x8 o;
#pragma unroll
      for (int j = 0; j < 8; ++j){
        float v = pwA[c]*b2f(L0[c][j]) + pwB[c]*b2f(L1[c][j])
                + pwC[c]*b2f(L2[c][j]) + pwD[c]*b2f(L3[c][j]);
        o[j] = f2b(v * pmv[c]);
      }
      *(bf16x8*)&valb[pdst[c]] = o;
    }
#undef DCN_STAGE
    __syncthreads();
    // ks-loop with weight prefetch: per-ks stride = 16*64 bf16x8 = 1024
    const bf16x8* wb = W8 + ((size_t)((ph*24)*16 + wave*2))*64 + lane;
    bf16x8 c0 = wb[0], c1 = wb[64];
    for (int ks = 0; ks < 24; ++ks){
      bf16x8 a0 = *(const bf16x8*)&valb[arow*VST + ks*32 + aquad*8];
      bf16x8 a1 = *(const bf16x8*)&valb[(16 + arow)*VST + ks*32 + aquad*8];
      bf16x8 n0, n1;
      if (ks < 23){ n0 = wb[(ks+1)*1024]; n1 = wb[(ks+1)*1024 + 64]; }
      acc[0][0] = MFMA16(a0, c0, acc[0][0]);
      acc[1][0] = MFMA16(a1, c0, acc[1][0]);
      acc[0][1] = MFMA16(a0, c1, acc[0][1]);
      acc[1][1] = MFMA16(a1, c1, acc[1][1]);
      if (ks < 23){ c0 = n0; c1 = n1; }
    }
  }
#pragma unroll
  for (int t = 0; t < 2; ++t){
    int f = wave*32 + t*16 + (lane & 15);
    float bias = db[f];
#pragma unroll
    for (int s = 0; s < 2; ++s)
#pragma unroll
      for (int r = 0; r < 4; ++r){
        int m = m0 + s*16 + aquad*4 + r;
        out[(size_t)m*256 + f] = fmaxf(acc[s][t][r] + bias, 0.f) + fcal[(size_t)m*256 + f];
      }
  }
}

extern "C" void kernel_launch(void* const* d_in, const int* in_sizes, int n_in,
                              void* d_out, int out_size, void* d_ws, size_t ws_size,
                              hipStream_t stream){
  const float* fine     = (const float*)d_in[0];
  const float* coarse   = (const float*)d_in[1];
  const float* attend_w = (const float*)d_in[2];
  const float* select_w = (const float*)d_in[3];
  const float* offset_w = (const float*)d_in[4];
  const float* om_w     = (const float*)d_in[5];
  const float* om_b     = (const float*)d_in[6];
  const float* dcn_w    = (const float*)d_in[7];
  const float* dcn_b    = (const float*)d_in[8];
  float* out = (float*)d_out;
  float* ws  = (float*)d_ws;

  float* gate = ws + OFS_GATE;
  float* part = ws + OFS_PART;
  short* cupb = (short*)(ws + OFS_CUPB);
  float* fcal = ws + OFS_FCAL;
  short* algb = (short*)(ws + OFS_ALGB);
  float* om   = ws + OFS_OM;
  short* dwb  = (short*)(ws + OFS_DWB);
  short* omwb = (short*)(ws + OFS_OMWB);
  short* swb  = (short*)(ws + OFS_SWB);
  short* owb  = (short*)(ws + OFS_OWB);

  hipLaunchKernelGGL(k_gap,  dim3(256),  dim3(256), 0, stream, fine, part);
  hipLaunchKernelGGL(k_misc, dim3(5220), dim3(256), 0, stream, part, attend_w, gate,
                     dcn_w, om_w, offset_w, select_w, dwb, omwb, owb, swb, coarse, cupb);
  hipLaunchKernelGGL(k_fa,   dim3(512),  dim3(512), 0, stream, fine, gate, swb, owb,
                     cupb, fcal, algb);
  hipLaunchKernelGGL(k_om,   dim3(256),  dim3(512), 0, stream, algb, omwb, om_b, om);
  hipLaunchKernelGGL(k_dcn,  dim3(512),  dim3(512), 0, stream, cupb, om, dwb, dcn_b, fcal, out);
  (void)in_sizes; (void)n_in; (void)out_size; (void)ws_size;
}

// Round 13
// 217.600 us; speedup vs baseline: 1.1708x; 1.0684x over previous
//
#include <hip/hip_runtime.h>
#include <math.h>

// B=4, H=W=64, C=256, DG=8, K=3, cpg=32; coarse: [4,32,32,256]

typedef __attribute__((ext_vector_type(8))) short bf16x8;
typedef __attribute__((ext_vector_type(4))) short bf16x4;
typedef __attribute__((ext_vector_type(4))) float f32x4;
#define MFMA16(a,b,c) __builtin_amdgcn_mfma_f32_16x16x32_bf16(a,b,c,0,0,0)

__device__ inline short f2b(float x){
  union { float f; unsigned u; } v; v.f = x;
  unsigned r = v.u + 0x7FFFu + ((v.u >> 16) & 1u);
  return (short)(r >> 16);
}
__device__ inline float b2f(short s){
  union { unsigned u; float f; } v;
  v.u = ((unsigned)(unsigned short)s) << 16;
  return v.f;
}

// workspace layout (float offsets)
#define OFS_GATE  1024u
#define OFS_PART  2048u        // f32 [256][256] gap partials
#define OFS_CUPB  264192u      // bf16 [4][64][64][256]
#define OFS_FCAL  4458496u     // f32  [16384][256]
#define OFS_ALGB  8652800u     // bf16 [16384][512]
#define OFS_OM    12847104u    // f32  [16384][216]
#define OFS_DWB   16386048u    // bf16 frag [72][16][64][8]
#define OFS_OMWB  16680960u    // bf16 frag [144][16][64][8]
#define OFS_SWB   17270784u    // bf16 frag [8][16][64][8]
#define OFS_OWB   17401856u    // bf16 frag [16][32][64][8]

// GAP partials: 256 blocks (b*64+chunk), float4 loads, LDS reduce, no atomics
__global__ __launch_bounds__(256) void k_gap(const float* __restrict__ fine,
                                             float* __restrict__ part){
  __shared__ float red[4*256];
  int b = blockIdx.x >> 6, chunk = blockIdx.x & 63;
  int c4 = threadIdx.x & 63, rl = threadIdx.x >> 6;
  const float4* F4 = (const float4*)fine;
  float4 s = {0.f,0.f,0.f,0.f};
  for (int it = 0; it < 16; ++it){
    int row = chunk*64 + it*4 + rl;
    float4 v = F4[((size_t)(b*4096 + row))*64 + c4];
    s.x += v.x; s.y += v.y; s.z += v.z; s.w += v.w;
  }
  *(float4*)&red[rl*256 + c4*4] = s;
  __syncthreads();
  int c = threadIdx.x;
  part[(size_t)blockIdx.x*256 + c] = red[c] + red[256+c] + red[512+c] + red[768+c];
}

// fused: attn (blocks 0-3) + weight frag cvt (dwb/omwb/owb/swb) + upsample->bf16
// attn path: 4-way partial sums + unroll to pipeline L2 loads -- the rolled
// serial FP chain (256 iters x ~200cy, only 16 waves on chip) was an exposed
// ~20us tail gating the whole dispatch.
__global__ __launch_bounds__(256) void k_misc(const float* __restrict__ part,
                                              const float* __restrict__ aw,
                                              float* __restrict__ gate,
                                              const float* __restrict__ dw,
                                              const float* __restrict__ omw,
                                              const float* __restrict__ ow,
                                              const float* __restrict__ sw,
                                              short* __restrict__ dwb,
                                              short* __restrict__ omwb,
                                              short* __restrict__ owb,
                                              short* __restrict__ swb,
                                              const float* __restrict__ coarse,
                                              short* __restrict__ cupb){
  int blk = blockIdx.x;
  if (blk < 4){
    __shared__ float m[256];
    int b = blk, f = threadIdx.x;
    float t0 = 0.f, t1 = 0.f, t2 = 0.f, t3 = 0.f;
#pragma unroll 4
    for (int ch = 0; ch < 64; ch += 4){
      t0 += part[(size_t)(b*64 + ch    )*256 + f];
      t1 += part[(size_t)(b*64 + ch + 1)*256 + f];
      t2 += part[(size_t)(b*64 + ch + 2)*256 + f];
      t3 += part[(size_t)(b*64 + ch + 3)*256 + f];
    }
    m[f] = ((t0 + t1) + (t2 + t3)) * (1.f/4096.f);
    __syncthreads();
    float s0 = 0.f, s1 = 0.f, s2 = 0.f, s3 = 0.f;
#pragma unroll 4
    for (int c = 0; c < 256; c += 4){
      s0 += m[c    ] * aw[(c    )*256 + f];
      s1 += m[c + 1] * aw[(c + 1)*256 + f];
      s2 += m[c + 2] * aw[(c + 2)*256 + f];
      s3 += m[c + 3] * aw[(c + 3)*256 + f];
    }
    float s = (s0 + s1) + (s2 + s3);
    gate[b*256 + f] = 1.f + 1.f/(1.f + expf(-s));
  } else if (blk < 292){
    int t = (blk - 4)*256 + threadIdx.x;         // 73728
    int l = t & 63, nt = (t >> 6) & 15, ksg = t >> 10;
    int n = nt*16 + (l & 15);
    int kb = ksg*32 + (l >> 4)*8;
    bf16x8 o;
#pragma unroll
    for (int j = 0; j < 8; ++j) o[j] = f2b(dw[(size_t)(kb + j)*256 + n]);
    ((bf16x8*)dwb)[t] = o;
  } else if (blk < 868){
    int t = (blk - 292)*256 + threadIdx.x;       // 147456
    int l = t & 63, nt = (t >> 6) & 15, ksg = t >> 10;
    int n = nt*16 + (l & 15);
    int kb = ksg*32 + (l >> 4)*8;
    bf16x8 o;
#pragma unroll
    for (int j = 0; j < 8; ++j)
      o[j] = (n < 216) ? f2b(omw[(size_t)(kb + j)*216 + n]) : (short)0;
    ((bf16x8*)omwb)[t] = o;
  } else if (blk < 996){
    int t = (blk - 868)*256 + threadIdx.x;       // 32768
    int l = t & 63, nt = (t >> 6) & 31, ksg = t >> 11;
    int n = nt*16 + (l & 15);
    int kb = ksg*32 + (l >> 4)*8;
    float sc = (kb >= 256) ? 2.f : 1.f;
    bf16x8 o;
#pragma unroll
    for (int j = 0; j < 8; ++j) o[j] = f2b(sc * ow[(size_t)(kb + j)*512 + n]);
    ((bf16x8*)owb)[t] = o;
  } else if (blk < 1124){
    int t = (blk - 996)*256 + threadIdx.x;       // 32768
    int l = t & 63, nt = (t >> 6) & 15, ksg = t >> 10;
    int n = nt*16 + (l & 15);
    int kb = ksg*32 + (l >> 4)*8;
    bf16x8 o;
#pragma unroll
    for (int j = 0; j < 8; ++j) o[j] = f2b(sw[(size_t)(kb + j)*256 + n]);
    ((bf16x8*)swb)[t] = o;
  } else {
    int idx = (blk - 1124)*256 + threadIdx.x;    // B*64*64*64 4-ch units
    int c4 = idx & 63, x = (idx >> 6) & 63, y = (idx >> 12) & 63, b = idx >> 18;
    float fy = 0.5f*y - 0.25f, fx = 0.5f*x - 0.25f;
    float yf = floorf(fy), xf = floorf(fx);
    float wy = fy - yf, wx = fx - xf;
    int r0 = max(0, min(31, (int)yf)), r1 = max(0, min(31, (int)yf + 1));
    int c0 = max(0, min(31, (int)xf)), c1 = max(0, min(31, (int)xf + 1));
    const float4* src = (const float4*)coarse;
    float4 v00 = src[((b*32 + r0)*32 + c0)*64 + c4];
    float4 v01 = src[((b*32 + r0)*32 + c1)*64 + c4];
    float4 v10 = src[((b*32 + r1)*32 + c0)*64 + c4];
    float4 v11 = src[((b*32 + r1)*32 + c1)*64 + c4];
    float w00 = (1.f-wy)*(1.f-wx), w01 = (1.f-wy)*wx, w10 = wy*(1.f-wx), w11 = wy*wx;
    bf16x4 o = { f2b(v00.x*w00 + v01.x*w01 + v10.x*w10 + v11.x*w11),
                 f2b(v00.y*w00 + v01.y*w01 + v10.y*w10 + v11.y*w11),
                 f2b(v00.z*w00 + v01.z*w01 + v10.z*w10 + v11.z*w11),
                 f2b(v00.w*w00 + v01.w*w01 + v10.w*w10 + v11.w*w11) };
    ((bf16x4*)cupb)[idx] = o;
  }
}

// fused fcal+align: 512 threads / 8 waves (16 waves/CU) to hide L2 weight
// latency; BM=32 grid 512. GEMM1: wave owns 32 n-cols; GEMM2: 64 n-cols.
// XCD-aware bijective swizzle for cupb K-tail locality.
#define FST 264
__global__ __launch_bounds__(512) void k_fa(const float* __restrict__ fine,
                                            const float* __restrict__ gate,
                                            const short* __restrict__ swb,
                                            const short* __restrict__ owb,
                                            const short* __restrict__ cupb,
                                            float* __restrict__ fcal,
                                            short* __restrict__ algb){
  __shared__ float g4[256];
  __shared__ short ab[32*FST];
  int bid = ((blockIdx.x & 7) << 6) | (blockIdx.x >> 3);  // bijective, 512%8==0
  int m0 = bid*32, b = m0 >> 12;
  int tid = threadIdx.x, lane = tid & 63, wave = tid >> 6;  // 8 waves
  int arow = lane & 15, aquad = lane >> 4;
  if (tid < 256) g4[tid] = gate[b*256 + tid];
  __syncthreads();
  const float4* F4 = (const float4*)(fine + (size_t)m0*256);
  const float4* G4 = (const float4*)g4;
  for (int it = 0; it < 4; ++it){
    int idx = it*512 + tid;               // 2048 = 32 rows x 64 c4
    int row = idx >> 6, c4 = idx & 63;
    float4 v = F4[row*64 + c4];
    float4 gg = G4[c4];
    bf16x4 s4 = { f2b(v.x*gg.x), f2b(v.y*gg.y), f2b(v.z*gg.z), f2b(v.w*gg.w) };
    *(bf16x4*)&ab[row*FST + c4*4] = s4;
  }
  __syncthreads();
  f32x4 acc[2][2];
#pragma unroll
  for (int s = 0; s < 2; ++s)
#pragma unroll
    for (int t = 0; t < 2; ++t) acc[s][t] = (f32x4){0.f,0.f,0.f,0.f};
  const bf16x8* W8 = (const bf16x8*)swb;
  for (int ks = 0; ks < 8; ++ks){
    bf16x8 a0 = *(const bf16x8*)&ab[arow*FST + ks*32 + aquad*8];
    bf16x8 a1 = *(const bf16x8*)&ab[(16 + arow)*FST + ks*32 + aquad*8];
    const bf16x8* wp = W8 + ((size_t)(ks*16 + wave*2))*64 + lane;
#pragma unroll
    for (int t = 0; t < 2; ++t){
      bf16x8 bw = wp[t*64];
      acc[0][t] = MFMA16(a0, bw, acc[0][t]);
      acc[1][t] = MFMA16(a1, bw, acc[1][t]);
    }
  }
  __syncthreads();
#pragma unroll
  for (int t = 0; t < 2; ++t){
    int f = wave*32 + t*16 + arow;
#pragma unroll
    for (int s = 0; s < 2; ++s)
#pragma unroll
      for (int r = 0; r < 4; ++r){
        int mloc = s*16 + aquad*4 + r;
        float v = acc[s][t][r];
        fcal[(size_t)(m0 + mloc)*256 + f] = v;
        ab[mloc*FST + f] = f2b(v);
      }
  }
  __syncthreads();
  f32x4 acc2[2][4];
#pragma unroll
  for (int s = 0; s < 2; ++s)
#pragma unroll
    for (int t = 0; t < 4; ++t) acc2[s][t] = (f32x4){0.f,0.f,0.f,0.f};
  const bf16x8* OW8 = (const bf16x8*)owb;
  for (int ks = 0; ks < 16; ++ks){
    bf16x8 a0, a1;
    if (ks < 8){
      a0 = *(const bf16x8*)&ab[arow*FST + ks*32 + aquad*8];
      a1 = *(const bf16x8*)&ab[(16 + arow)*FST + ks*32 + aquad*8];
    } else {
      int ko = (ks - 8)*32 + aquad*8;
      a0 = *(const bf16x8*)(cupb + (size_t)(m0 + arow)*256 + ko);
      a1 = *(const bf16x8*)(cupb + (size_t)(m0 + 16 + arow)*256 + ko);
    }
    const bf16x8* wp = OW8 + ((size_t)(ks*32 + wave*4))*64 + lane;
#pragma unroll
    for (int t = 0; t < 4; ++t){
      bf16x8 bw = wp[t*64];
      acc2[0][t] = MFMA16(a0, bw, acc2[0][t]);
      acc2[1][t] = MFMA16(a1, bw, acc2[1][t]);
    }
  }
#pragma unroll
  for (int t = 0; t < 4; ++t){
    int n = wave*64 + t*16 + arow;
#pragma unroll
    for (int s = 0; s < 2; ++s)
#pragma unroll
      for (int r = 0; r < 4; ++r){
        int m = m0 + s*16 + aquad*4 + r;
        algb[(size_t)m*512 + n] = f2b(acc2[s][t][r]);
      }
  }
}

// om conv3x3 as MFMA implicit GEMM. v2 (round-5 best config, BANKED: six
// structural variants all landed 57-96us; latency-pinned ~58us, not touched).
// BM=64, BN=256, 1x8 waves, acc[4][2], 264-pad, 6 stage phases, weight
// prefetch. Mask channels pre-sigmoided for k_dcn.
#define XST2 264
__global__ __launch_bounds__(512) void k_om(const short* __restrict__ algb,
                                            const short* __restrict__ omwb,
                                            const float* __restrict__ omb,
                                            float* __restrict__ om){
  __shared__ short xbuf[66*XST2];   // 34848 B
  int blk = ((blockIdx.x & 7) << 5) | (blockIdx.x >> 3);  // bijective, 256%8==0
  int m0 = blk*64;
  int b = m0 >> 12, y = (m0 >> 6) & 63;
  int tid = threadIdx.x;
  int lane = tid & 63, wave = tid >> 6;      // 8 waves
  int arow = lane & 15, aquad = lane >> 4;
  f32x4 acc[4][2];
#pragma unroll
  for (int mi = 0; mi < 4; ++mi)
#pragma unroll
    for (int t = 0; t < 2; ++t) acc[mi][t] = (f32x4){0.f,0.f,0.f,0.f};
  const bf16x8* W8 = (const bf16x8*)omwb;
  for (int ky = 0; ky < 3; ++ky){
    int yy = y + ky - 1;
    if ((unsigned)yy >= 64u) continue;       // block-uniform
    const short* srow = algb + (size_t)((b*64 + yy)*64)*512;
    for (int h = 0; h < 2; ++h){
      __syncthreads();
      for (int it = 0; it < 5; ++it){
        int u = it*512 + tid;                // 2112 = 66 cols x 32 units
        if (u < 2112){
          int xx = u >> 5, cu = u & 31;
          int gx = xx - 1;
          bf16x8 v = (bf16x8){0,0,0,0,0,0,0,0};
          if ((unsigned)gx < 64u)
            v = *(const bf16x8*)(srow + (size_t)gx*512 + h*256 + cu*8);
          *(bf16x8*)&xbuf[xx*XST2 + cu*8] = v;
        }
      }
      __syncthreads();
#pragma unroll
      for (int kx = 0; kx < 3; ++kx){
        // wb: base for (ky,kx,h,s=0); per-s stride = 16*64 bf16x8 = 1024
        const bf16x8* wb = W8 + ((size_t)((ky*48 + kx*16 + h*8)*16 + wave*2))*64 + lane;
        bf16x8 c0 = wb[0], c1 = wb[64];
        for (int s = 0; s < 8; ++s){
          bf16x8 a[4];
#pragma unroll
          for (int mi = 0; mi < 4; ++mi)
            a[mi] = *(const bf16x8*)&xbuf[(mi*16 + arow + kx)*XST2 + s*32 + aquad*8];
          bf16x8 n0, n1;
          if (s < 7){ n0 = wb[(s+1)*1024]; n1 = wb[(s+1)*1024 + 64]; }
#pragma unroll
          for (int mi = 0; mi < 4; ++mi) acc[mi][0] = MFMA16(a[mi], c0, acc[mi][0]);
#pragma unroll
          for (int mi = 0; mi < 4; ++mi) acc[mi][1] = MFMA16(a[mi], c1, acc[mi][1]);
          if (s < 7){ c0 = n0; c1 = n1; }
        }
      }
    }
  }
#pragma unroll
  for (int t = 0; t < 2; ++t){
    int f = wave*32 + t*16 + arow;
    if (f < 216){
      float bias = omb[f];
      bool is_mask = (f >= 144);
#pragma unroll
      for (int mi = 0; mi < 4; ++mi)
#pragma unroll
        for (int r = 0; r < 4; ++r){
          int m = m0 + mi*16 + aquad*4 + r;
          float v = acc[mi][t][r] + bias;
          if (is_mask) v = 1.f/(1.f + expf(-v));
          om[(size_t)m*216 + f] = v;
        }
    }
  }
}

// DCNv2: M-tile 32, 512-thread blocks (2 blocks/CU). Gather phase: r10's
// proven depth-2 DCN_STAGE pipeline (BANKED at 218.75us total; depth-3 with
// %3 slot rotation regressed +14us -- the &1 parity ping-pong is the
// SROA-safe sweet spot; r11's cross-loop param arrays spilled to scratch).
// launch_bounds(512,4). Weight prefetch kept in ks-loop.
#define VST 776
__global__ __launch_bounds__(512, 4) void k_dcn(const short* __restrict__ cupb,
                                                const float* __restrict__ om,
                                                const short* __restrict__ dwb,
                                                const float* __restrict__ db,
                                                const float* __restrict__ fcal,
                                                float* __restrict__ out){
  __shared__ short valb[32*VST];   // 49664 B
  int bid = ((blockIdx.x & 7) << 6) | (blockIdx.x >> 3);  // XCD swizzle, bijective
  int m0 = bid*32;
  int b = m0 >> 12, y = (m0 & 4095) >> 6, x0 = m0 & 63;
  int tid = threadIdx.x;
  int lane = tid & 63, wave = tid >> 6;    // 8 waves
  int unit = tid >> 2, lane4 = tid & 3;    // 128 units x 4 lanes
  int arow = lane & 15, aquad = lane >> 4;
  f32x4 acc[2][2];
#pragma unroll
  for (int s = 0; s < 2; ++s)
#pragma unroll
    for (int t = 0; t < 2; ++t) acc[s][t] = (f32x4){0.f,0.f,0.f,0.f};
  const short* cpb = cupb + (size_t)b*4096*256;
  const bf16x8* W8 = (const bf16x8*)dwb;

  for (int ph = 0; ph < 3; ++ph){
    __syncthreads();
    // 768 samples (32 rows x 8 g x 3 taps); 128 units, 6 iters, 8 ch/lane.
    // 2-deep pipeline: PARAM+GATHER(it+1) issued before BLEND(it).
    bf16x8 L0[2], L1[2], L2[2], L3[2];
    float pwA[2], pwB[2], pwC[2], pwD[2], pmv[2];
    int pdst[2];
#define DCN_STAGE(S, IT)                                                     \
    {                                                                        \
      int u = (IT)*128 + unit;                                               \
      int i = u / 24; int r = u - i*24; int g = r / 3; int kk = r - g*3;     \
      const float* omp = om + (size_t)(m0 + i)*216;                          \
      int k = ph*3 + kk;                                                     \
      float dy = omp[(g*9 + k)*2 + 0];                                       \
      float dx = omp[(g*9 + k)*2 + 1];                                       \
      float mv = omp[144 + g*9 + k];                                         \
      float yp = (float)(y + ph - 1) + dy;                                   \
      float xp = (float)(x0 + i + kk - 1) + dx;                              \
      float yf = floorf(yp), xf = floorf(xp);                                \
      float wy = yp - yf, wx = xp - xf;                                      \
      int iy = (int)yf, ix = (int)xf;                                        \
      float wA = (1.f-wy)*(1.f-wx), wB = (1.f-wy)*wx;                        \
      float wC = wy*(1.f-wx), wD = wy*wx;                                    \
      bool y0ok = (unsigned)iy < 64u, y1ok = (unsigned)(iy+1) < 64u;         \
      bool x0ok = (unsigned)ix < 64u, x1ok = (unsigned)(ix+1) < 64u;         \
      if (!(y0ok && x0ok)) wA = 0.f;                                         \
      if (!(y0ok && x1ok)) wB = 0.f;                                         \
      if (!(y1ok && x0ok)) wC = 0.f;                                         \
      if (!(y1ok && x1ok)) wD = 0.f;                                         \
      int y0c = min(max(iy, 0), 63), y1c = min(max(iy + 1, 0), 63);          \
      int x0c = min(max(ix, 0), 63), x1c = min(max(ix + 1, 0), 63);          \
      int cofs = g*32 + lane4*8;                                             \
      L0[S] = *(const bf16x8*)(cpb + (size_t)(y0c*64 + x0c)*256 + cofs);     \
      L1[S] = *(const bf16x8*)(cpb + (size_t)(y0c*64 + x1c)*256 + cofs);     \
      L2[S] = *(const bf16x8*)(cpb + (size_t)(y1c*64 + x0c)*256 + cofs);     \
      L3[S] = *(const bf16x8*)(cpb + (size_t)(y1c*64 + x1c)*256 + cofs);     \
      pwA[S] = wA; pwB[S] = wB; pwC[S] = wC; pwD[S] = wD; pmv[S] = mv;       \
      pdst[S] = i*VST + kk*256 + g*32 + lane4*8;                             \
    }
    DCN_STAGE(0, 0)
#pragma unroll
    for (int it = 0; it < 6; ++it){
      int c = it & 1, nx = c ^ 1;
      if (it < 5){ DCN_STAGE(nx, it + 1) }
      bf16x8 o;
#pragma unroll
      for (int j = 0; j < 8; ++j){
        float v = pwA[c]*b2f(L0[c][j]) + pwB[c]*b2f(L1[c][j])
                + pwC[c]*b2f(L2[c][j]) + pwD[c]*b2f(L3[c][j]);
        o[j] = f2b(v * pmv[c]);
      }
      *(bf16x8*)&valb[pdst[c]] = o;
    }
#undef DCN_STAGE
    __syncthreads();
    // ks-loop with weight prefetch: per-ks stride = 16*64 bf16x8 = 1024
    const bf16x8* wb = W8 + ((size_t)((ph*24)*16 + wave*2))*64 + lane;
    bf16x8 c0 = wb[0], c1 = wb[64];
    for (int ks = 0; ks < 24; ++ks){
      bf16x8 a0 = *(const bf16x8*)&valb[arow*VST + ks*32 + aquad*8];
      bf16x8 a1 = *(const bf16x8*)&valb[(16 + arow)*VST + ks*32 + aquad*8];
      bf16x8 n0, n1;
      if (ks < 23){ n0 = wb[(ks+1)*1024]; n1 = wb[(ks+1)*1024 + 64]; }
      acc[0][0] = MFMA16(a0, c0, acc[0][0]);
      acc[1][0] = MFMA16(a1, c0, acc[1][0]);
      acc[0][1] = MFMA16(a0, c1, acc[0][1]);
      acc[1][1] = MFMA16(a1, c1, acc[1][1]);
      if (ks < 23){ c0 = n0; c1 = n1; }
    }
  }
#pragma unroll
  for (int t = 0; t < 2; ++t){
    int f = wave*32 + t*16 + (lane & 15);
    float bias = db[f];
#pragma unroll
    for (int s = 0; s < 2; ++s)
#pragma unroll
      for (int r = 0; r < 4; ++r){
        int m = m0 + s*16 + aquad*4 + r;
        out[(size_t)m*256 + f] = fmaxf(acc[s][t][r] + bias, 0.f) + fcal[(size_t)m*256 + f];
      }
  }
}

extern "C" void kernel_launch(void* const* d_in, const int* in_sizes, int n_in,
                              void* d_out, int out_size, void* d_ws, size_t ws_size,
                              hipStream_t stream){
  const float* fine     = (const float*)d_in[0];
  const float* coarse   = (const float*)d_in[1];
  const float* attend_w = (const float*)d_in[2];
  const float* select_w = (const float*)d_in[3];
  const float* offset_w = (const float*)d_in[4];
  const float* om_w     = (const float*)d_in[5];
  const float* om_b     = (const float*)d_in[6];
  const float* dcn_w    = (const float*)d_in[7];
  const float* dcn_b    = (const float*)d_in[8];
  float* out = (float*)d_out;
  float* ws  = (float*)d_ws;

  float* gate = ws + OFS_GATE;
  float* part = ws + OFS_PART;
  short* cupb = (short*)(ws + OFS_CUPB);
  float* fcal = ws + OFS_FCAL;
  short* algb = (short*)(ws + OFS_ALGB);
  float* om   = ws + OFS_OM;
  short* dwb  = (short*)(ws + OFS_DWB);
  short* omwb = (short*)(ws + OFS_OMWB);
  short* swb  = (short*)(ws + OFS_SWB);
  short* owb  = (short*)(ws + OFS_OWB);

  hipLaunchKernelGGL(k_gap,  dim3(256),  dim3(256), 0, stream, fine, part);
  hipLaunchKernelGGL(k_misc, dim3(5220), dim3(256), 0, stream, part, attend_w, gate,
                     dcn_w, om_w, offset_w, select_w, dwb, omwb, owb, swb, coarse, cupb);
  hipLaunchKernelGGL(k_fa,   dim3(512),  dim3(512), 0, stream, fine, gate, swb, owb,
                     cupb, fcal, algb);
  hipLaunchKernelGGL(k_om,   dim3(256),  dim3(512), 0, stream, algb, omwb, om_b, om);
  hipLaunchKernelGGL(k_dcn,  dim3(512),  dim3(512), 0, stream, cupb, om, dwb, dcn_b, fcal, out);
  (void)in_sizes; (void)n_in; (void)out_size; (void)ws_size;
}

// Round 14
// 207.607 us; speedup vs baseline: 1.2271x; 1.0481x over previous
//
#include <hip/hip_runtime.h>
#include <math.h>

// B=4, H=W=64, C=256, DG=8, K=3, cpg=32; coarse: [4,32,32,256]

typedef __attribute__((ext_vector_type(8))) short bf16x8;
typedef __attribute__((ext_vector_type(4))) short bf16x4;
typedef __attribute__((ext_vector_type(4))) float f32x4;
#define MFMA16(a,b,c) __builtin_amdgcn_mfma_f32_16x16x32_bf16(a,b,c,0,0,0)

__device__ inline short f2b(float x){
  union { float f; unsigned u; } v; v.f = x;
  unsigned r = v.u + 0x7FFFu + ((v.u >> 16) & 1u);
  return (short)(r >> 16);
}
__device__ inline float b2f(short s){
  union { unsigned u; float f; } v;
  v.u = ((unsigned)(unsigned short)s) << 16;
  return v.f;
}

// workspace layout (float offsets)
#define OFS_GATE  1024u
#define OFS_PART  2048u        // f32 [256][256] gap partials
#define OFS_CUPB  264192u      // bf16 [4][64][64][256]
#define OFS_FCAL  4458496u     // f32  [16384][256]
#define OFS_ALGB  8652800u     // bf16 [16384][512]
#define OFS_OM    12847104u    // (unused after k_om/k_dcn fusion)
#define OFS_DWB   16386048u    // bf16 frag [72][16][64][8]
#define OFS_OMWB  16680960u    // bf16 frag [144][16][64][8]
#define OFS_SWB   17270784u    // bf16 frag [8][16][64][8]
#define OFS_OWB   17401856u    // bf16 frag [16][32][64][8]

// GAP partials: 256 blocks (b*64+chunk), float4 loads, LDS reduce, no atomics
__global__ __launch_bounds__(256) void k_gap(const float* __restrict__ fine,
                                             float* __restrict__ part){
  __shared__ float red[4*256];
  int b = blockIdx.x >> 6, chunk = blockIdx.x & 63;
  int c4 = threadIdx.x & 63, rl = threadIdx.x >> 6;
  const float4* F4 = (const float4*)fine;
  float4 s = {0.f,0.f,0.f,0.f};
  for (int it = 0; it < 16; ++it){
    int row = chunk*64 + it*4 + rl;
    float4 v = F4[((size_t)(b*4096 + row))*64 + c4];
    s.x += v.x; s.y += v.y; s.z += v.z; s.w += v.w;
  }
  *(float4*)&red[rl*256 + c4*4] = s;
  __syncthreads();
  int c = threadIdx.x;
  part[(size_t)blockIdx.x*256 + c] = red[c] + red[256+c] + red[512+c] + red[768+c];
}

// fused: attn (blocks 0-3, 4-way partial sums) + weight frag cvt + upsample
__global__ __launch_bounds__(256) void k_misc(const float* __restrict__ part,
                                              const float* __restrict__ aw,
                                              float* __restrict__ gate,
                                              const float* __restrict__ dw,
                                              const float* __restrict__ omw,
                                              const float* __restrict__ ow,
                                              const float* __restrict__ sw,
                                              short* __restrict__ dwb,
                                              short* __restrict__ omwb,
                                              short* __restrict__ owb,
                                              short* __restrict__ swb,
                                              const float* __restrict__ coarse,
                                              short* __restrict__ cupb){
  int blk = blockIdx.x;
  if (blk < 4){
    __shared__ float m[256];
    int b = blk, f = threadIdx.x;
    float t0 = 0.f, t1 = 0.f, t2 = 0.f, t3 = 0.f;
#pragma unroll 4
    for (int ch = 0; ch < 64; ch += 4){
      t0 += part[(size_t)(b*64 + ch    )*256 + f];
      t1 += part[(size_t)(b*64 + ch + 1)*256 + f];
      t2 += part[(size_t)(b*64 + ch + 2)*256 + f];
      t3 += part[(size_t)(b*64 + ch + 3)*256 + f];
    }
    m[f] = ((t0 + t1) + (t2 + t3)) * (1.f/4096.f);
    __syncthreads();
    float s0 = 0.f, s1 = 0.f, s2 = 0.f, s3 = 0.f;
#pragma unroll 4
    for (int c = 0; c < 256; c += 4){
      s0 += m[c    ] * aw[(c    )*256 + f];
      s1 += m[c + 1] * aw[(c + 1)*256 + f];
      s2 += m[c + 2] * aw[(c + 2)*256 + f];
      s3 += m[c + 3] * aw[(c + 3)*256 + f];
    }
    float s = (s0 + s1) + (s2 + s3);
    gate[b*256 + f] = 1.f + 1.f/(1.f + expf(-s));
  } else if (blk < 292){
    int t = (blk - 4)*256 + threadIdx.x;         // 73728
    int l = t & 63, nt = (t >> 6) & 15, ksg = t >> 10;
    int n = nt*16 + (l & 15);
    int kb = ksg*32 + (l >> 4)*8;
    bf16x8 o;
#pragma unroll
    for (int j = 0; j < 8; ++j) o[j] = f2b(dw[(size_t)(kb + j)*256 + n]);
    ((bf16x8*)dwb)[t] = o;
  } else if (blk < 868){
    int t = (blk - 292)*256 + threadIdx.x;       // 147456
    int l = t & 63, nt = (t >> 6) & 15, ksg = t >> 10;
    int n = nt*16 + (l & 15);
    int kb = ksg*32 + (l >> 4)*8;
    bf16x8 o;
#pragma unroll
    for (int j = 0; j < 8; ++j)
      o[j] = (n < 216) ? f2b(omw[(size_t)(kb + j)*216 + n]) : (short)0;
    ((bf16x8*)omwb)[t] = o;
  } else if (blk < 996){
    int t = (blk - 868)*256 + threadIdx.x;       // 32768
    int l = t & 63, nt = (t >> 6) & 31, ksg = t >> 11;
    int n = nt*16 + (l & 15);
    int kb = ksg*32 + (l >> 4)*8;
    float sc = (kb >= 256) ? 2.f : 1.f;
    bf16x8 o;
#pragma unroll
    for (int j = 0; j < 8; ++j) o[j] = f2b(sc * ow[(size_t)(kb + j)*512 + n]);
    ((bf16x8*)owb)[t] = o;
  } else if (blk < 1124){
    int t = (blk - 996)*256 + threadIdx.x;       // 32768
    int l = t & 63, nt = (t >> 6) & 15, ksg = t >> 10;
    int n = nt*16 + (l & 15);
    int kb = ksg*32 + (l >> 4)*8;
    bf16x8 o;
#pragma unroll
    for (int j = 0; j < 8; ++j) o[j] = f2b(sw[(size_t)(kb + j)*256 + n]);
    ((bf16x8*)swb)[t] = o;
  } else {
    int idx = (blk - 1124)*256 + threadIdx.x;    // B*64*64*64 4-ch units
    int c4 = idx & 63, x = (idx >> 6) & 63, y = (idx >> 12) & 63, b = idx >> 18;
    float fy = 0.5f*y - 0.25f, fx = 0.5f*x - 0.25f;
    float yf = floorf(fy), xf = floorf(fx);
    float wy = fy - yf, wx = fx - xf;
    int r0 = max(0, min(31, (int)yf)), r1 = max(0, min(31, (int)yf + 1));
    int c0 = max(0, min(31, (int)xf)), c1 = max(0, min(31, (int)xf + 1));
    const float4* src = (const float4*)coarse;
    float4 v00 = src[((b*32 + r0)*32 + c0)*64 + c4];
    float4 v01 = src[((b*32 + r0)*32 + c1)*64 + c4];
    float4 v10 = src[((b*32 + r1)*32 + c0)*64 + c4];
    float4 v11 = src[((b*32 + r1)*32 + c1)*64 + c4];
    float w00 = (1.f-wy)*(1.f-wx), w01 = (1.f-wy)*wx, w10 = wy*(1.f-wx), w11 = wy*wx;
    bf16x4 o = { f2b(v00.x*w00 + v01.x*w01 + v10.x*w10 + v11.x*w11),
                 f2b(v00.y*w00 + v01.y*w01 + v10.y*w10 + v11.y*w11),
                 f2b(v00.z*w00 + v01.z*w01 + v10.z*w10 + v11.z*w11),
                 f2b(v00.w*w00 + v01.w*w01 + v10.w*w10 + v11.w*w11) };
    ((bf16x4*)cupb)[idx] = o;
  }
}

// fused fcal+align: 512 threads / 8 waves (16 waves/CU); BM=32 grid 512.
#define FST 264
__global__ __launch_bounds__(512) void k_fa(const float* __restrict__ fine,
                                            const float* __restrict__ gate,
                                            const short* __restrict__ swb,
                                            const short* __restrict__ owb,
                                            const short* __restrict__ cupb,
                                            float* __restrict__ fcal,
                                            short* __restrict__ algb){
  __shared__ float g4[256];
  __shared__ short ab[32*FST];
  int bid = ((blockIdx.x & 7) << 6) | (blockIdx.x >> 3);  // bijective, 512%8==0
  int m0 = bid*32, b = m0 >> 12;
  int tid = threadIdx.x, lane = tid & 63, wave = tid >> 6;  // 8 waves
  int arow = lane & 15, aquad = lane >> 4;
  if (tid < 256) g4[tid] = gate[b*256 + tid];
  __syncthreads();
  const float4* F4 = (const float4*)(fine + (size_t)m0*256);
  const float4* G4 = (const float4*)g4;
  for (int it = 0; it < 4; ++it){
    int idx = it*512 + tid;               // 2048 = 32 rows x 64 c4
    int row = idx >> 6, c4 = idx & 63;
    float4 v = F4[row*64 + c4];
    float4 gg = G4[c4];
    bf16x4 s4 = { f2b(v.x*gg.x), f2b(v.y*gg.y), f2b(v.z*gg.z), f2b(v.w*gg.w) };
    *(bf16x4*)&ab[row*FST + c4*4] = s4;
  }
  __syncthreads();
  f32x4 acc[2][2];
#pragma unroll
  for (int s = 0; s < 2; ++s)
#pragma unroll
    for (int t = 0; t < 2; ++t) acc[s][t] = (f32x4){0.f,0.f,0.f,0.f};
  const bf16x8* W8 = (const bf16x8*)swb;
  for (int ks = 0; ks < 8; ++ks){
    bf16x8 a0 = *(const bf16x8*)&ab[arow*FST + ks*32 + aquad*8];
    bf16x8 a1 = *(const bf16x8*)&ab[(16 + arow)*FST + ks*32 + aquad*8];
    const bf16x8* wp = W8 + ((size_t)(ks*16 + wave*2))*64 + lane;
#pragma unroll
    for (int t = 0; t < 2; ++t){
      bf16x8 bw = wp[t*64];
      acc[0][t] = MFMA16(a0, bw, acc[0][t]);
      acc[1][t] = MFMA16(a1, bw, acc[1][t]);
    }
  }
  __syncthreads();
#pragma unroll
  for (int t = 0; t < 2; ++t){
    int f = wave*32 + t*16 + arow;
#pragma unroll
    for (int s = 0; s < 2; ++s)
#pragma unroll
      for (int r = 0; r < 4; ++r){
        int mloc = s*16 + aquad*4 + r;
        float v = acc[s][t][r];
        fcal[(size_t)(m0 + mloc)*256 + f] = v;
        ab[mloc*FST + f] = f2b(v);
      }
  }
  __syncthreads();
  f32x4 acc2[2][4];
#pragma unroll
  for (int s = 0; s < 2; ++s)
#pragma unroll
    for (int t = 0; t < 4; ++t) acc2[s][t] = (f32x4){0.f,0.f,0.f,0.f};
  const bf16x8* OW8 = (const bf16x8*)owb;
  for (int ks = 0; ks < 16; ++ks){
    bf16x8 a0, a1;
    if (ks < 8){
      a0 = *(const bf16x8*)&ab[arow*FST + ks*32 + aquad*8];
      a1 = *(const bf16x8*)&ab[(16 + arow)*FST + ks*32 + aquad*8];
    } else {
      int ko = (ks - 8)*32 + aquad*8;
      a0 = *(const bf16x8*)(cupb + (size_t)(m0 + arow)*256 + ko);
      a1 = *(const bf16x8*)(cupb + (size_t)(m0 + 16 + arow)*256 + ko);
    }
    const bf16x8* wp = OW8 + ((size_t)(ks*32 + wave*4))*64 + lane;
#pragma unroll
    for (int t = 0; t < 4; ++t){
      bf16x8 bw = wp[t*64];
      acc2[0][t] = MFMA16(a0, bw, acc2[0][t]);
      acc2[1][t] = MFMA16(a1, bw, acc2[1][t]);
    }
  }
#pragma unroll
  for (int t = 0; t < 4; ++t){
    int n = wave*64 + t*16 + arow;
#pragma unroll
    for (int s = 0; s < 2; ++s)
#pragma unroll
      for (int r = 0; r < 4; ++r){
        int m = m0 + s*16 + aquad*4 + r;
        algb[(size_t)m*512 + n] = f2b(acc2[s][t][r]);
      }
  }
}

// FUSED om-conv + DCNv2. Grid 512 (k_dcn geometry: BM=32, x0 in {0,32}),
// 512 threads, 2 blocks/CU. Phase 1: conv3x3 om for THIS tile's 32 pixels
// (v2 structure shrunk to BM=32: acc[2][2], 34-col stage, weight prefetch),
// mask pre-sigmoided, written to LDS om_s (om is tile-local: k_dcn only ever
// read its own m-rows -> no HBM round-trip, no dispatch gap, param loads
// become LDS broadcasts). Phase 2: r10's banked k_dcn body verbatim with
// omp -> om_s. LDS: valb(49.7K) time-shares with xbuf(18K); +om_s(27.6K)
// = 77.3KB -> 2 blocks/CU kept. Cost: omwb stream 2x (r1 measured +3us).
#define XOM 264
#define VST 776
#define OMS 216
__global__ __launch_bounds__(512, 4) void k_omdcn(const short* __restrict__ algb,
                                                  const short* __restrict__ omwb,
                                                  const float* __restrict__ omb,
                                                  const short* __restrict__ cupb,
                                                  const short* __restrict__ dwb,
                                                  const float* __restrict__ db,
                                                  const float* __restrict__ fcal,
                                                  float* __restrict__ out){
  __shared__ __align__(16) char smem[77312];
  short* xbuf = (short*)smem;                    // [34][264] shorts (OM phase)
  short* valb = (short*)smem;                    // [32][776] shorts (DCN phase)
  float* om_s = (float*)(smem + 49664);          // [32][216] f32
  int bid = ((blockIdx.x & 7) << 6) | (blockIdx.x >> 3);  // bijective, 512%8==0
  int m0 = bid*32;
  int b = m0 >> 12, y = (m0 & 4095) >> 6, x0 = m0 & 63;
  int tid = threadIdx.x;
  int lane = tid & 63, wave = tid >> 6;    // 8 waves
  int unit = tid >> 2, lane4 = tid & 3;    // 128 units x 4 lanes
  int arow = lane & 15, aquad = lane >> 4;

  // ---------------- Phase 1: om conv3x3 -> om_s ----------------
  {
    f32x4 acc[2][2];
#pragma unroll
    for (int mi = 0; mi < 2; ++mi)
#pragma unroll
      for (int t = 0; t < 2; ++t) acc[mi][t] = (f32x4){0.f,0.f,0.f,0.f};
    const bf16x8* W8 = (const bf16x8*)omwb;
    for (int ky = 0; ky < 3; ++ky){
      int yy = y + ky - 1;
      if ((unsigned)yy >= 64u) continue;   // block-uniform
      const short* srow = algb + (size_t)((b*64 + yy)*64)*512;
      for (int h = 0; h < 2; ++h){
        __syncthreads();
        for (int it = 0; it < 3; ++it){
          int u = it*512 + tid;            // 1088 = 34 cols x 32 units
          if (u < 1088){
            int xx = u >> 5, cu = u & 31;
            int gx = x0 - 1 + xx;
            bf16x8 v = (bf16x8){0,0,0,0,0,0,0,0};
            if ((unsigned)gx < 64u)
              v = *(const bf16x8*)(srow + (size_t)gx*512 + h*256 + cu*8);
            *(bf16x8*)&xbuf[xx*XOM + cu*8] = v;
          }
        }
        __syncthreads();
#pragma unroll
        for (int kx = 0; kx < 3; ++kx){
          const bf16x8* wb = W8 + ((size_t)((ky*48 + kx*16 + h*8)*16 + wave*2))*64 + lane;
          bf16x8 c0 = wb[0], c1 = wb[64];
          for (int s = 0; s < 8; ++s){
            bf16x8 a0 = *(const bf16x8*)&xbuf[(arow + kx)*XOM + s*32 + aquad*8];
            bf16x8 a1 = *(const bf16x8*)&xbuf[(16 + arow + kx)*XOM + s*32 + aquad*8];
            bf16x8 n0, n1;
            if (s < 7){ n0 = wb[(s+1)*1024]; n1 = wb[(s+1)*1024 + 64]; }
            acc[0][0] = MFMA16(a0, c0, acc[0][0]);
            acc[1][0] = MFMA16(a1, c0, acc[1][0]);
            acc[0][1] = MFMA16(a0, c1, acc[0][1]);
            acc[1][1] = MFMA16(a1, c1, acc[1][1]);
            if (s < 7){ c0 = n0; c1 = n1; }
          }
        }
      }
    }
#pragma unroll
    for (int t = 0; t < 2; ++t){
      int f = wave*32 + t*16 + arow;
      if (f < 216){
        float bias = omb[f];
        bool is_mask = (f >= 144);
#pragma unroll
        for (int mi = 0; mi < 2; ++mi)
#pragma unroll
          for (int r = 0; r < 4; ++r){
            int mloc = mi*16 + aquad*4 + r;
            float v = acc[mi][t][r] + bias;
            if (is_mask) v = 1.f/(1.f + expf(-v));
            om_s[mloc*OMS + f] = v;
          }
      }
    }
  }

  // ---------------- Phase 2: DCNv2 (r10 body, omp -> LDS) ----------------
  f32x4 acc[2][2];
#pragma unroll
  for (int s = 0; s < 2; ++s)
#pragma unroll
    for (int t = 0; t < 2; ++t) acc[s][t] = (f32x4){0.f,0.f,0.f,0.f};
  const short* cpb = cupb + (size_t)b*4096*256;
  const bf16x8* W8 = (const bf16x8*)dwb;

  for (int ph = 0; ph < 3; ++ph){
    __syncthreads();
    // 768 samples (32 rows x 8 g x 3 taps); 128 units, 6 iters, 8 ch/lane.
    // 2-deep pipeline: PARAM+GATHER(it+1) issued before BLEND(it).
    bf16x8 L0[2], L1[2], L2[2], L3[2];
    float pwA[2], pwB[2], pwC[2], pwD[2], pmv[2];
    int pdst[2];
#define DCN_STAGE(S, IT)                                                     \
    {                                                                        \
      int u = (IT)*128 + unit;                                               \
      int i = u / 24; int r = u - i*24; int g = r / 3; int kk = r - g*3;     \
      const float* omp = om_s + i*OMS;                                       \
      int k = ph*3 + kk;                                                     \
      float dy = omp[(g*9 + k)*2 + 0];                                       \
      float dx = omp[(g*9 + k)*2 + 1];                                       \
      float mv = omp[144 + g*9 + k];                                         \
      float yp = (float)(y + ph - 1) + dy;                                   \
      float xp = (float)(x0 + i + kk - 1) + dx;                              \
      float yf = floorf(yp), xf = floorf(xp);                                \
      float wy = yp - yf, wx = xp - xf;                                      \
      int iy = (int)yf, ix = (int)xf;                                        \
      float wA = (1.f-wy)*(1.f-wx), wB = (1.f-wy)*wx;                        \
      float wC = wy*(1.f-wx), wD = wy*wx;                                    \
      bool y0ok = (unsigned)iy < 64u, y1ok = (unsigned)(iy+1) < 64u;         \
      bool x0ok = (unsigned)ix < 64u, x1ok = (unsigned)(ix+1) < 64u;         \
      if (!(y0ok && x0ok)) wA = 0.f;                                         \
      if (!(y0ok && x1ok)) wB = 0.f;                                         \
      if (!(y1ok && x0ok)) wC = 0.f;                                         \
      if (!(y1ok && x1ok)) wD = 0.f;                                         \
      int y0c = min(max(iy, 0), 63), y1c = min(max(iy + 1, 0), 63);          \
      int x0c = min(max(ix, 0), 63), x1c = min(max(ix + 1, 0), 63);          \
      int cofs = g*32 + lane4*8;                                             \
      L0[S] = *(const bf16x8*)(cpb + (size_t)(y0c*64 + x0c)*256 + cofs);     \
      L1[S] = *(const bf16x8*)(cpb + (size_t)(y0c*64 + x1c)*256 + cofs);     \
      L2[S] = *(const bf16x8*)(cpb + (size_t)(y1c*64 + x0c)*256 + cofs);     \
      L3[S] = *(const bf16x8*)(cpb + (size_t)(y1c*64 + x1c)*256 + cofs);     \
      pwA[S] = wA; pwB[S] = wB; pwC[S] = wC; pwD[S] = wD; pmv[S] = mv;       \
      pdst[S] = i*VST + kk*256 + g*32 + lane4*8;                             \
    }
    DCN_STAGE(0, 0)
#pragma unroll
    for (int it = 0; it < 6; ++it){
      int c = it & 1, nx = c ^ 1;
      if (it < 5){ DCN_STAGE(nx, it + 1) }
      bf16x8 o;
#pragma unroll
      for (int j = 0; j < 8; ++j){
        float v = pwA[c]*b2f(L0[c][j]) + pwB[c]*b2f(L1[c][j])
                + pwC[c]*b2f(L2[c][j]) + pwD[c]*b2f(L3[c][j]);
        o[j] = f2b(v * pmv[c]);
      }
      *(bf16x8*)&valb[pdst[c]] = o;
    }
#undef DCN_STAGE
    __syncthreads();
    // ks-loop with weight prefetch: per-ks stride = 16*64 bf16x8 = 1024
    const bf16x8* wb = W8 + ((size_t)((ph*24)*16 + wave*2))*64 + lane;
    bf16x8 c0 = wb[0], c1 = wb[64];
    for (int ks = 0; ks < 24; ++ks){
      bf16x8 a0 = *(const bf16x8*)&valb[arow*VST + ks*32 + aquad*8];
      bf16x8 a1 = *(const bf16x8*)&valb[(16 + arow)*VST + ks*32 + aquad*8];
      bf16x8 n0, n1;
      if (ks < 23){ n0 = wb[(ks+1)*1024]; n1 = wb[(ks+1)*1024 + 64]; }
      acc[0][0] = MFMA16(a0, c0, acc[0][0]);
      acc[1][0] = MFMA16(a1, c0, acc[1][0]);
      acc[0][1] = MFMA16(a0, c1, acc[0][1]);
      acc[1][1] = MFMA16(a1, c1, acc[1][1]);
      if (ks < 23){ c0 = n0; c1 = n1; }
    }
  }
#pragma unroll
  for (int t = 0; t < 2; ++t){
    int f = wave*32 + t*16 + (lane & 15);
    float bias = db[f];
#pragma unroll
    for (int s = 0; s < 2; ++s)
#pragma unroll
      for (int r = 0; r < 4; ++r){
        int m = m0 + s*16 + aquad*4 + r;
        out[(size_t)m*256 + f] = fmaxf(acc[s][t][r] + bias, 0.f) + fcal[(size_t)m*256 + f];
      }
  }
}

extern "C" void kernel_launch(void* const* d_in, const int* in_sizes, int n_in,
                              void* d_out, int out_size, void* d_ws, size_t ws_size,
                              hipStream_t stream){
  const float* fine     = (const float*)d_in[0];
  const float* coarse   = (const float*)d_in[1];
  const float* attend_w = (const float*)d_in[2];
  const float* select_w = (const float*)d_in[3];
  const float* offset_w = (const float*)d_in[4];
  const float* om_w     = (const float*)d_in[5];
  const float* om_b     = (const float*)d_in[6];
  const float* dcn_w    = (const float*)d_in[7];
  const float* dcn_b    = (const float*)d_in[8];
  float* out = (float*)d_out;
  float* ws  = (float*)d_ws;

  float* gate = ws + OFS_GATE;
  float* part = ws + OFS_PART;
  short* cupb = (short*)(ws + OFS_CUPB);
  float* fcal = ws + OFS_FCAL;
  short* algb = (short*)(ws + OFS_ALGB);
  short* dwb  = (short*)(ws + OFS_DWB);
  short* omwb = (short*)(ws + OFS_OMWB);
  short* swb  = (short*)(ws + OFS_SWB);
  short* owb  = (short*)(ws + OFS_OWB);

  hipLaunchKernelGGL(k_gap,  dim3(256),  dim3(256), 0, stream, fine, part);
  hipLaunchKernelGGL(k_misc, dim3(5220), dim3(256), 0, stream, part, attend_w, gate,
                     dcn_w, om_w, offset_w, select_w, dwb, omwb, owb, swb, coarse, cupb);
  hipLaunchKernelGGL(k_fa,   dim3(512),  dim3(512), 0, stream, fine, gate, swb, owb,
                     cupb, fcal, algb);
  hipLaunchKernelGGL(k_omdcn, dim3(512), dim3(512), 0, stream, algb, omwb, om_b,
                     cupb, dwb, dcn_b, fcal, out);
  (void)in_sizes; (void)n_in; (void)out_size; (void)ws_size;
}